// Round 1
// baseline (5234.269 us; speedup 1.0000x reference)
//
#include <hip/hip_runtime.h>
#include <math.h>

#define DEV __device__ __forceinline__

constexpr int B_ = 4, N_ = 4096, D_ = 512, E_ = 4, H_ = 1024, NF_ = 32;
constexpr int KL_ = 2048, T_ = KL_ + 1;          // 2049
constexpr int TOK_ = B_ * T_;                    // 8196

DEV float gelu_f(float x){ return 0.5f * x * (1.0f + erff(x * 0.7071067811865475f)); }

DEV float wave_sum(float v){
  #pragma unroll
  for (int off = 32; off > 0; off >>= 1) v += __shfl_down(v, off, 64);
  return v;
}

// 256-thread block sum, result broadcast to all threads. sm must have >=4 floats.
DEV float block_sum256(float v, float* sm){
  v = wave_sum(v);
  int lane = threadIdx.x & 63, wid = threadIdx.x >> 6;
  if (lane == 0) sm[wid] = v;
  __syncthreads();
  if (threadIdx.x == 0) sm[0] = sm[0] + sm[1] + sm[2] + sm[3];
  __syncthreads();
  float r = sm[0];
  __syncthreads();
  return r;
}

// rmsnorm1 + sigmoid score + xs = x_n * score.  One block per row, 256 thr, D=512.
__global__ void k_rms_score(const float* __restrict__ x, const float* __restrict__ g,
                            const float* __restrict__ aw, const float* __restrict__ ab,
                            float* __restrict__ xs, float* __restrict__ scores){
  __shared__ float sm[4];
  int row = blockIdx.x; int tid = threadIdx.x;
  const float* xr = x + (size_t)row * D_;
  float v0 = xr[tid], v1 = xr[tid + 256];
  float ss = block_sum256(v0 * v0 + v1 * v1, sm);
  float n = fmaxf(sqrtf(ss), 1e-12f);
  float inv = 22.627416997969522f / n;   // sqrt(512)
  float xn0 = v0 * inv * g[tid], xn1 = v1 * inv * g[tid + 256];
  float z = block_sum256(xn0 * aw[tid] + xn1 * aw[tid + 256], sm) + ab[0];
  float s = 1.0f / (1.0f + expf(-z));
  float* o = xs + (size_t)row * D_;
  o[tid] = xn0 * s; o[tid + 256] = xn1 * s;
  if (tid == 0) scores[row] = s;
}

// top-k selection flags via exact rank (ties -> lower index wins, matches lax.top_k)
__global__ void k_select(const float* __restrict__ scores, int* __restrict__ flags){
  __shared__ float s[N_];
  int b = blockIdx.y; int tid = threadIdx.x;
  int i = blockIdx.x * 256 + tid;
  for (int j = tid; j < N_; j += 256) s[j] = scores[(size_t)b * N_ + j];
  __syncthreads();
  float si = s[i];
  int cnt = 0;
  for (int j = 0; j < N_; j++){
    float sj = s[j];
    cnt += (sj > si) || (sj == si && j < i);
  }
  flags[(size_t)b * N_ + i] = (cnt < KL_) ? 1 : 0;
}

// compact selected indices in ascending order. One wave per batch.
__global__ void k_compact(const int* __restrict__ flags, int* __restrict__ idx){
  int b = blockIdx.x; int lane = threadIdx.x;
  int base = 0;
  for (int chunk = 0; chunk < N_ / 64; chunk++){
    int t = chunk * 64 + lane;
    int fl = flags[(size_t)b * N_ + t];
    unsigned long long m = __ballot(fl != 0);
    int pre = __popcll(m & ((1ull << lane) - 1ull));
    if (fl) idx[(size_t)b * KL_ + base + pre] = t;
    base += __popcll(m);
  }
}

__global__ void k_gather(const float* __restrict__ xs, const int* __restrict__ idx,
                         float* __restrict__ xcat){
  size_t i = (size_t)blockIdx.x * 256 + threadIdx.x;
  int d = (int)(i & 511);
  int p = (int)((i >> 9) & (KL_ - 1));
  int b = (int)(i >> 20);              // 9 + 11 bits
  int tok = idx[(size_t)b * KL_ + p];
  xcat[((size_t)b * T_ + p) * D_ + d] = xs[((size_t)b * N_ + tok) * D_ + d];
}

// extra row = sum of unselected xs rows
__global__ void k_extra(const float* __restrict__ xs, const int* __restrict__ flags,
                        float* __restrict__ xcat){
  int b = blockIdx.y;
  int d = blockIdx.x * 256 + threadIdx.x;
  float acc = 0.0f;
  const float* xp = xs + (size_t)b * N_ * D_ + d;
  const int* fb = flags + (size_t)b * N_;
  for (int i = 0; i < N_; i++) if (!fb[i]) acc += xp[(size_t)i * D_];
  xcat[((size_t)b * T_ + KL_) * D_ + d] = acc;
}

__global__ void k_rms2(const float* __restrict__ xc, const float* __restrict__ g,
                       float* __restrict__ xn2){
  __shared__ float sm[4];
  int row = blockIdx.x; int tid = threadIdx.x;
  const float* xr = xc + (size_t)row * D_;
  float v0 = xr[tid], v1 = xr[tid + 256];
  float ss = block_sum256(v0 * v0 + v1 * v1, sm);
  float n = fmaxf(sqrtf(ss), 1e-12f);
  float inv = 22.627416997969522f / n;
  float* o = xn2 + (size_t)row * D_;
  o[tid] = v0 * inv * g[tid];
  o[tid + 256] = v1 * inv * g[tid + 256];
}

// gate logits + softmax + atomic mean accumulation. One wave per token.
__global__ void k_gate(const float* __restrict__ xn2, const float* __restrict__ gw,
                       float* __restrict__ gate, float* __restrict__ gsum){
  int row = blockIdx.x; int lane = threadIdx.x;
  const float* xr = xn2 + (size_t)row * D_;
  const float4* gw4 = (const float4*)gw;
  float l0 = 0, l1 = 0, l2 = 0, l3 = 0;
  for (int i = 0; i < 8; i++){
    int d = lane * 8 + i;
    float xv = xr[d];
    float4 w = gw4[d];
    l0 += xv * w.x; l1 += xv * w.y; l2 += xv * w.z; l3 += xv * w.w;
  }
  l0 = wave_sum(l0); l1 = wave_sum(l1); l2 = wave_sum(l2); l3 = wave_sum(l3);
  if (lane == 0){
    float m = fmaxf(fmaxf(l0, l1), fmaxf(l2, l3));
    float e0 = expf(l0 - m), e1 = expf(l1 - m), e2 = expf(l2 - m), e3 = expf(l3 - m);
    float inv = 1.0f / (e0 + e1 + e2 + e3);
    float g0 = e0 * inv, g1 = e1 * inv, g2 = e2 * inv, g3 = e3 * inv;
    float* gr = gate + (size_t)row * 4;
    gr[0] = g0; gr[1] = g1; gr[2] = g2; gr[3] = g3;
    atomicAdd(&gsum[0], g0); atomicAdd(&gsum[1], g1);
    atomicAdd(&gsum[2], g2); atomicAdd(&gsum[3], g3);
  }
}

// f32 tiled GEMM: C(MxN) = A(MxK) @ B(KxN), row-major, N%64==0, K%16==0.
// EPI 0: store; EPI 1: C = gelu(acc) * scale[row*sstride]; EPI 2: C += acc.
template<int EPI>
__global__ void gemm64(const float* __restrict__ A, const float* __restrict__ Bm,
                       float* __restrict__ C, int M, int Nn, int K,
                       const float* __restrict__ scale, int sstride){
  __shared__ float As[16][65];
  __shared__ float Bs[16][65];
  int tid = threadIdx.x;
  int bm = blockIdx.y * 64, bn = blockIdx.x * 64;
  int ty = tid >> 4, tx = tid & 15;
  float acc[4][4] = {};
  for (int k0 = 0; k0 < K; k0 += 16){
    #pragma unroll
    for (int i = 0; i < 4; i++){
      int l = tid + i * 256; int m = l >> 4, k = l & 15; int gm = bm + m;
      As[k][m] = (gm < M) ? A[(size_t)gm * K + k0 + k] : 0.0f;
    }
    #pragma unroll
    for (int i = 0; i < 4; i++){
      int l = tid + i * 256; int n = l & 63, k = l >> 6;
      Bs[k][n] = Bm[(size_t)(k0 + k) * Nn + bn + n];
    }
    __syncthreads();
    #pragma unroll
    for (int k = 0; k < 16; k++){
      float a[4], b[4];
      #pragma unroll
      for (int i = 0; i < 4; i++) a[i] = As[k][ty * 4 + i];
      #pragma unroll
      for (int j = 0; j < 4; j++) b[j] = Bs[k][tx * 4 + j];
      #pragma unroll
      for (int i = 0; i < 4; i++)
        #pragma unroll
        for (int j = 0; j < 4; j++) acc[i][j] += a[i] * b[j];
    }
    __syncthreads();
  }
  #pragma unroll
  for (int i = 0; i < 4; i++){
    int row = bm + ty * 4 + i;
    if (row >= M) continue;
    float s = (EPI == 1) ? scale[(size_t)row * sstride] : 0.0f;
    #pragma unroll
    for (int j = 0; j < 4; j++){
      int col = bn + tx * 4 + j;
      size_t ci = (size_t)row * Nn + col;
      if (EPI == 0) C[ci] = acc[i][j];
      else if (EPI == 1) C[ci] = gelu_f(acc[i][j]) * s;
      else C[ci] += acc[i][j];
    }
  }
}

// out[token, ooff+f] = sum_d (maybe-maxpool3 x)[token,d] * w[f,d]; one wave/token.
template<bool MP>
__global__ void k_dot32(const float* __restrict__ xn2, const float* __restrict__ w,
                        float* __restrict__ out, int ostride, int ooff){
  int token = blockIdx.x; int lane = threadIdx.x;
  int t = token % T_;
  int f = lane & 31, half = lane >> 5;
  const float* xr = xn2 + (size_t)token * D_ + half * 256;
  const float* wr = w + (size_t)f * D_ + half * 256;
  float acc = 0.0f;
  for (int d = 0; d < 256; d++){
    float v = xr[d];
    if (MP){
      if (t > 0)        v = fmaxf(v, xr[d - D_]);
      if (t < T_ - 1)   v = fmaxf(v, xr[d + D_]);
    }
    acc += v * wr[d];
  }
  acc += __shfl_down(acc, 32, 64);
  if (lane < 32) out[(size_t)token * ostride + ooff + lane] = acc;
}

// conv1d 32->32 channels over time within each batch sample; one wave per token.
template<int KW, int PAD, int COFF>
__global__ void k_conv(const float* __restrict__ xb, const float* __restrict__ w,
                       float* __restrict__ cat){
  int token = blockIdx.x; int lane = threadIdx.x;
  int b = token / T_, t = token % T_;
  int f = lane & 31, half = lane >> 5;
  const float* wf = w + (size_t)f * 32 * KW + half * 16 * KW;
  float acc = 0.0f;
  for (int k = 0; k < KW; k++){
    int tt = t + k - PAD;
    if (tt < 0 || tt >= T_) continue;
    const float* xr = xb + ((size_t)b * T_ + tt) * 32 + half * 16;
    #pragma unroll
    for (int c = 0; c < 16; c++) acc += xr[c] * wf[c * KW + k];
  }
  acc += __shfl_down(acc, 32, 64);
  if (lane < 32) cat[(size_t)token * 128 + COFF + lane] = acc;
}

__global__ void k_bnstat(const float* __restrict__ cat, float* __restrict__ bn){
  __shared__ float sm[4];
  int c = blockIdx.x; int tid = threadIdx.x;
  float s = 0, q = 0;
  for (int i = tid; i < TOK_; i += 256){
    float v = cat[(size_t)i * 128 + c]; s += v; q += v * v;
  }
  float S = block_sum256(s, sm);
  float Q = block_sum256(q, sm);
  if (tid == 0){
    float mu = S / (float)TOK_;
    bn[c] = mu;
    bn[128 + c] = Q / (float)TOK_ - mu * mu;   // biased var, matches jnp.var
  }
}

__global__ void k_bnact(float* __restrict__ cat, const float* __restrict__ bn,
                        const float* __restrict__ g, const float* __restrict__ b){
  int i = blockIdx.x * 256 + threadIdx.x;
  int c = i & 127;
  float v = cat[i];
  v = (v - bn[c]) * rsqrtf(bn[128 + c] + 1e-5f) * g[c] + b[c];
  cat[i] = gelu_f(v);
}

__global__ void k_final(const float* __restrict__ xcat, const float* __restrict__ moe,
                        const float* __restrict__ iout, const float* __restrict__ pb,
                        float* __restrict__ out){
  size_t i = (size_t)blockIdx.x * 256 + threadIdx.x;
  int d = (int)(i & 511);
  out[i] = gelu_f(xcat[i] + moe[i] + iout[i] + pb[d]);
}

__global__ void k_loss(const float* __restrict__ gsum, float* __restrict__ o){
  if (threadIdx.x == 0){
    float l = 0;
    for (int e = 0; e < E_; e++){ float m = gsum[e] / (float)TOK_; l += m * m; }
    o[0] = (float)E_ * l;
  }
}

extern "C" void kernel_launch(void* const* d_in, const int* in_sizes, int n_in,
                              void* d_out, int out_size, void* d_ws, size_t ws_size,
                              hipStream_t stream){
  const float* x      = (const float*)d_in[0];
  // d_in[1] = left_k (int, ==2048) — shapes are static, hardcoded
  const float* gamma1 = (const float*)d_in[2];
  const float* gamma2 = (const float*)d_in[3];
  const float* attn_w = (const float*)d_in[4];
  const float* attn_b = (const float*)d_in[5];
  const float* gate_w = (const float*)d_in[6];
  const float* ew1    = (const float*)d_in[7];
  const float* ew2    = (const float*)d_in[8];
  const float* bott_w = (const float*)d_in[9];
  const float* w39    = (const float*)d_in[10];
  const float* w19    = (const float*)d_in[11];
  const float* w9     = (const float*)d_in[12];
  const float* mp_w   = (const float*)d_in[13];
  const float* bn_g   = (const float*)d_in[14];
  const float* bn_b   = (const float*)d_in[15];
  const float* proj_w = (const float*)d_in[16];
  const float* proj_b = (const float*)d_in[17];
  float* out = (float*)d_out;

  float* ws = (float*)d_ws;
  size_t off = 0;
  auto alloc = [&](size_t n){ size_t o = off; off += (n + 63) & ~(size_t)63; return o; };
  size_t big = (size_t)TOK_ * H_;                       // h-buffer 8196*1024
  size_t xsz = (size_t)B_ * N_ * D_;                    // xs 4*4096*512
  size_t f_xs   = alloc(big > xsz ? big : xsz);         // xs, later reused as h
  size_t f_sc   = alloc(B_ * N_);
  size_t f_fl   = alloc(B_ * N_);
  size_t f_idx  = alloc(B_ * KL_);
  size_t f_xcat = alloc((size_t)TOK_ * D_);
  size_t f_xn2  = alloc((size_t)TOK_ * D_);
  size_t f_gate = alloc(TOK_ * E_);
  size_t f_gs   = alloc(64);
  size_t f_moe  = alloc((size_t)TOK_ * D_);
  size_t f_xb   = alloc((size_t)TOK_ * NF_);
  size_t f_cat  = alloc((size_t)TOK_ * 128);
  size_t f_bn   = alloc(256);
  size_t f_iout = alloc((size_t)TOK_ * D_);
  (void)ws_size; (void)in_sizes; (void)n_in; (void)out_size;

  float* xs   = ws + f_xs;
  float* sc   = ws + f_sc;
  int*   fl   = (int*)(ws + f_fl);
  int*   idx  = (int*)(ws + f_idx);
  float* xcat = ws + f_xcat;
  float* xn2  = ws + f_xn2;
  float* gate = ws + f_gate;
  float* gs   = ws + f_gs;
  float* moe  = ws + f_moe;
  float* xb   = ws + f_xb;
  float* cat  = ws + f_cat;
  float* bn   = ws + f_bn;
  float* iout = ws + f_iout;

  hipMemsetAsync(moe, 0, (size_t)TOK_ * D_ * sizeof(float), stream);
  hipMemsetAsync(gs, 0, 64 * sizeof(float), stream);

  k_rms_score<<<B_ * N_, 256, 0, stream>>>(x, gamma1, attn_w, attn_b, xs, sc);
  k_select<<<dim3(N_ / 256, B_), 256, 0, stream>>>(sc, fl);
  k_compact<<<B_, 64, 0, stream>>>(fl, idx);
  k_gather<<<(B_ * KL_ * D_) / 256, 256, 0, stream>>>(xs, idx, xcat);
  k_extra<<<dim3(D_ / 256, B_), 256, 0, stream>>>(xs, fl, xcat);
  k_rms2<<<TOK_, 256, 0, stream>>>(xcat, gamma2, xn2);
  k_gate<<<TOK_, 64, 0, stream>>>(xn2, gate_w, gate, gs);

  int mtiles = (TOK_ + 63) / 64;   // 129
  float* hbuf = xs;                // reuse xs region as per-expert h buffer
  for (int e = 0; e < E_; e++){
    gemm64<1><<<dim3(H_ / 64, mtiles), 256, 0, stream>>>(
        xn2, ew1 + (size_t)e * D_ * H_, hbuf, TOK_, H_, D_, gate + e, E_);
    gemm64<2><<<dim3(D_ / 64, mtiles), 256, 0, stream>>>(
        hbuf, ew2 + (size_t)e * H_ * D_, moe, TOK_, D_, H_, nullptr, 0);
  }

  k_dot32<false><<<TOK_, 64, 0, stream>>>(xn2, bott_w, xb, 32, 0);
  k_dot32<true><<<TOK_, 64, 0, stream>>>(xn2, mp_w, cat, 128, 96);
  k_conv<39, 19, 0><<<TOK_, 64, 0, stream>>>(xb, w39, cat);
  k_conv<19, 9, 32><<<TOK_, 64, 0, stream>>>(xb, w19, cat);
  k_conv<9, 4, 64><<<TOK_, 64, 0, stream>>>(xb, w9, cat);
  k_bnstat<<<128, 256, 0, stream>>>(cat, bn);
  k_bnact<<<(TOK_ * 128) / 256, 256, 0, stream>>>(cat, bn, bn_g, bn_b);
  gemm64<0><<<dim3(D_ / 64, mtiles), 256, 0, stream>>>(
      cat, proj_w, iout, TOK_, D_, 128, nullptr, 0);
  k_final<<<((size_t)TOK_ * D_) / 256, 256, 0, stream>>>(xcat, moe, iout, proj_b, out);
  k_loss<<<1, 64, 0, stream>>>(gs, out + (size_t)TOK_ * D_);
}

// Round 2
// 2741.511 us; speedup vs baseline: 1.9093x; 1.9093x over previous
//
#include <hip/hip_runtime.h>
#include <math.h>

#define DEV __device__ __forceinline__

constexpr int B_ = 4, N_ = 4096, D_ = 512, E_ = 4, H_ = 1024, NF_ = 32;
constexpr int KL_ = 2048, T_ = KL_ + 1;          // 2049
constexpr int TOK_ = B_ * T_;                    // 8196

DEV float gelu_f(float x){ return 0.5f * x * (1.0f + erff(x * 0.7071067811865475f)); }

DEV float wave_sum(float v){
  #pragma unroll
  for (int off = 32; off > 0; off >>= 1) v += __shfl_down(v, off, 64);
  return v;
}

DEV float block_sum256(float v, float* sm){
  v = wave_sum(v);
  int lane = threadIdx.x & 63, wid = threadIdx.x >> 6;
  if (lane == 0) sm[wid] = v;
  __syncthreads();
  if (threadIdx.x == 0) sm[0] = sm[0] + sm[1] + sm[2] + sm[3];
  __syncthreads();
  float r = sm[0];
  __syncthreads();
  return r;
}

// rmsnorm1 + sigmoid score + xs = x_n * score.
__global__ void k_rms_score(const float* __restrict__ x, const float* __restrict__ g,
                            const float* __restrict__ aw, const float* __restrict__ ab,
                            float* __restrict__ xs, float* __restrict__ scores){
  __shared__ float sm[4];
  int row = blockIdx.x; int tid = threadIdx.x;
  const float* xr = x + (size_t)row * D_;
  float v0 = xr[tid], v1 = xr[tid + 256];
  float ss = block_sum256(v0 * v0 + v1 * v1, sm);
  float n = fmaxf(sqrtf(ss), 1e-12f);
  float inv = 22.627416997969522f / n;   // sqrt(512)
  float xn0 = v0 * inv * g[tid], xn1 = v1 * inv * g[tid + 256];
  float z = block_sum256(xn0 * aw[tid] + xn1 * aw[tid + 256], sm) + ab[0];
  float s = 1.0f / (1.0f + expf(-z));
  float* o = xs + (size_t)row * D_;
  o[tid] = xn0 * s; o[tid + 256] = xn1 * s;
  if (tid == 0) scores[row] = s;
}

// top-k selection flags via exact rank (ties -> lower index, matches lax.top_k)
__global__ void k_select(const float* __restrict__ scores, int* __restrict__ flags){
  __shared__ float s[N_];
  int b = blockIdx.y; int tid = threadIdx.x;
  int i = blockIdx.x * 256 + tid;
  const float4* src = (const float4*)(scores + (size_t)b * N_);
  for (int j = tid; j < N_ / 4; j += 256) ((float4*)s)[j] = src[j];
  __syncthreads();
  float si = s[i];
  int cnt = 0;
  for (int j = 0; j < N_; j += 4){
    float4 v = *(const float4*)&s[j];
    cnt += (v.x > si) || (v.x == si && (j + 0) < i);
    cnt += (v.y > si) || (v.y == si && (j + 1) < i);
    cnt += (v.z > si) || (v.z == si && (j + 2) < i);
    cnt += (v.w > si) || (v.w == si && (j + 3) < i);
  }
  flags[(size_t)b * N_ + i] = (cnt < KL_) ? 1 : 0;
}

__global__ void k_compact(const int* __restrict__ flags, int* __restrict__ idx){
  int b = blockIdx.x; int lane = threadIdx.x;
  int base = 0;
  for (int chunk = 0; chunk < N_ / 64; chunk++){
    int t = chunk * 64 + lane;
    int fl = flags[(size_t)b * N_ + t];
    unsigned long long m = __ballot(fl != 0);
    int pre = __popcll(m & ((1ull << lane) - 1ull));
    if (fl) idx[(size_t)b * KL_ + base + pre] = t;
    base += __popcll(m);
  }
}

__global__ void k_gather(const float* __restrict__ xs, const int* __restrict__ idx,
                         float* __restrict__ xcat){
  size_t i = (size_t)blockIdx.x * 256 + threadIdx.x;
  int d = (int)(i & 511);
  int p = (int)((i >> 9) & (KL_ - 1));
  int b = (int)(i >> 20);
  int tok = idx[(size_t)b * KL_ + p];
  xcat[((size_t)b * T_ + p) * D_ + d] = xs[((size_t)b * N_ + tok) * D_ + d];
}

// extra row = sum of unselected xs rows: coalesced two-stage reduction
__global__ void k_extra1(const float* __restrict__ xs, const int* __restrict__ flags,
                         float* __restrict__ part){
  int b = blockIdx.y, blk = blockIdx.x;
  int tid = threadIdx.x;
  const int* fb = flags + (size_t)b * N_ + blk * 256;
  const float2* xp = (const float2*)(xs + ((size_t)b * N_ + blk * 256) * D_) + tid;
  float2 acc = {0.f, 0.f};
  for (int i = 0; i < 256; i++){
    if (!fb[i]){
      float2 v = xp[(size_t)i * 256];
      acc.x += v.x; acc.y += v.y;
    }
  }
  float* pr = part + ((size_t)(b * 16 + blk)) * D_;
  pr[tid * 2] = acc.x; pr[tid * 2 + 1] = acc.y;
}

__global__ void k_extra2(const float* __restrict__ part, float* __restrict__ xcat){
  int b = blockIdx.y; int d = blockIdx.x * 256 + threadIdx.x;
  float s = 0.f;
  for (int i = 0; i < 16; i++) s += part[((size_t)(b * 16 + i)) * D_ + d];
  xcat[((size_t)b * T_ + KL_) * D_ + d] = s;
}

__global__ void k_rms2(const float* __restrict__ xc, const float* __restrict__ g,
                       float* __restrict__ xn2){
  __shared__ float sm[4];
  int row = blockIdx.x; int tid = threadIdx.x;
  const float* xr = xc + (size_t)row * D_;
  float v0 = xr[tid], v1 = xr[tid + 256];
  float ss = block_sum256(v0 * v0 + v1 * v1, sm);
  float n = fmaxf(sqrtf(ss), 1e-12f);
  float inv = 22.627416997969522f / n;
  float* o = xn2 + (size_t)row * D_;
  o[tid] = v0 * inv * g[tid];
  o[tid + 256] = v1 * inv * g[tid + 256];
}

__global__ void k_gate(const float* __restrict__ xn2, const float* __restrict__ gw,
                       float* __restrict__ gate, float* __restrict__ gsum){
  int row = blockIdx.x; int lane = threadIdx.x;
  const float* xr = xn2 + (size_t)row * D_;
  const float4* gw4 = (const float4*)gw;
  float l0 = 0, l1 = 0, l2 = 0, l3 = 0;
  for (int i = 0; i < 8; i++){
    int d = lane * 8 + i;
    float xv = xr[d];
    float4 w = gw4[d];
    l0 += xv * w.x; l1 += xv * w.y; l2 += xv * w.z; l3 += xv * w.w;
  }
  l0 = wave_sum(l0); l1 = wave_sum(l1); l2 = wave_sum(l2); l3 = wave_sum(l3);
  if (lane == 0){
    float m = fmaxf(fmaxf(l0, l1), fmaxf(l2, l3));
    float e0 = expf(l0 - m), e1 = expf(l1 - m), e2 = expf(l2 - m), e3 = expf(l3 - m);
    float inv = 1.0f / (e0 + e1 + e2 + e3);
    float g0 = e0 * inv, g1 = e1 * inv, g2 = e2 * inv, g3 = e3 * inv;
    float* gr = gate + (size_t)row * 4;
    gr[0] = g0; gr[1] = g1; gr[2] = g2; gr[3] = g3;
    atomicAdd(&gsum[0], g0); atomicAdd(&gsum[1], g1);
    atomicAdd(&gsum[2], g2); atomicAdd(&gsum[3], g3);
  }
}

// f32 tiled GEMM (unchanged this round)
template<int EPI>
__global__ void gemm64(const float* __restrict__ A, const float* __restrict__ Bm,
                       float* __restrict__ C, int M, int Nn, int K,
                       const float* __restrict__ scale, int sstride){
  __shared__ float As[16][65];
  __shared__ float Bs[16][65];
  int tid = threadIdx.x;
  int bm = blockIdx.y * 64, bn = blockIdx.x * 64;
  int ty = tid >> 4, tx = tid & 15;
  float acc[4][4] = {};
  for (int k0 = 0; k0 < K; k0 += 16){
    #pragma unroll
    for (int i = 0; i < 4; i++){
      int l = tid + i * 256; int m = l >> 4, k = l & 15; int gm = bm + m;
      As[k][m] = (gm < M) ? A[(size_t)gm * K + k0 + k] : 0.0f;
    }
    #pragma unroll
    for (int i = 0; i < 4; i++){
      int l = tid + i * 256; int n = l & 63, k = l >> 6;
      Bs[k][n] = Bm[(size_t)(k0 + k) * Nn + bn + n];
    }
    __syncthreads();
    #pragma unroll
    for (int k = 0; k < 16; k++){
      float a[4], b[4];
      #pragma unroll
      for (int i = 0; i < 4; i++) a[i] = As[k][ty * 4 + i];
      #pragma unroll
      for (int j = 0; j < 4; j++) b[j] = Bs[k][tx * 4 + j];
      #pragma unroll
      for (int i = 0; i < 4; i++)
        #pragma unroll
        for (int j = 0; j < 4; j++) acc[i][j] += a[i] * b[j];
    }
    __syncthreads();
  }
  #pragma unroll
  for (int i = 0; i < 4; i++){
    int row = bm + ty * 4 + i;
    if (row >= M) continue;
    float s = (EPI == 1) ? scale[(size_t)row * sstride] : 0.0f;
    #pragma unroll
    for (int j = 0; j < 4; j++){
      int col = bn + tx * 4 + j;
      size_t ci = (size_t)row * Nn + col;
      if (EPI == 0) C[ci] = acc[i][j];
      else if (EPI == 1) C[ci] = gelu_f(acc[i][j]) * s;
      else C[ci] += acc[i][j];
    }
  }
}

// 1x1 conv (optionally maxpool3 input): 64-token tile, 32 out-features.
// thread = (tok = tid&63, grp = tid>>6), each computes 8 features.
template<bool MP>
__global__ void k_1x1(const float* __restrict__ xn2, const float* __restrict__ w,
                      float* __restrict__ out, int ostride, int ooff){
  __shared__ float Xs[64 * 33];
  __shared__ float Ws[32 * 40];   // Ws[d][f], plane pitch 40 (16B-aligned reads)
  int tid = threadIdx.x;
  int G0 = blockIdx.x * 64;
  int tok = tid & 63, grp = tid >> 6;
  float acc[8] = {};
  for (int d0 = 0; d0 < D_; d0 += 32){
    // stage X (vectorized float4 over d)
    for (int j = tid; j < 64 * 8; j += 256){
      int tt = j >> 3, dc = (j & 7) * 4;
      int g = G0 + tt;
      float4 v = {0.f, 0.f, 0.f, 0.f};
      if (g < TOK_){
        const float* p = xn2 + (size_t)g * D_ + d0 + dc;
        v = *(const float4*)p;
        if (MP){
          int t = g % T_;
          if (t > 0){ float4 u = *(const float4*)(p - D_);
            v.x = fmaxf(v.x, u.x); v.y = fmaxf(v.y, u.y);
            v.z = fmaxf(v.z, u.z); v.w = fmaxf(v.w, u.w); }
          if (t < T_ - 1){ float4 u = *(const float4*)(p + D_);
            v.x = fmaxf(v.x, u.x); v.y = fmaxf(v.y, u.y);
            v.z = fmaxf(v.z, u.z); v.w = fmaxf(v.w, u.w); }
        }
      }
      float* xd = &Xs[tt * 33 + dc];
      xd[0] = v.x; xd[1] = v.y; xd[2] = v.z; xd[3] = v.w;
    }
    // stage W transposed: Ws[d*40 + f] = w[f][d0+d]
    for (int j = tid; j < 32 * 32; j += 256){
      int f = j >> 5, d = j & 31;
      Ws[d * 40 + f] = w[(size_t)f * D_ + d0 + d];
    }
    __syncthreads();
    const float* xr = &Xs[tok * 33];
    #pragma unroll 8
    for (int d = 0; d < 32; d++){
      float xv = xr[d];
      const float4* w4 = (const float4*)&Ws[d * 40 + grp * 8];
      float4 a = w4[0], b = w4[1];
      acc[0] += xv * a.x; acc[1] += xv * a.y; acc[2] += xv * a.z; acc[3] += xv * a.w;
      acc[4] += xv * b.x; acc[5] += xv * b.y; acc[6] += xv * b.z; acc[7] += xv * b.w;
    }
    __syncthreads();
  }
  int g = G0 + tok;
  if (g < TOK_){
    #pragma unroll
    for (int j = 0; j < 8; j++) out[(size_t)g * ostride + ooff + grp * 8 + j] = acc[j];
  }
}

// repack conv weight (oc,ic,KW) -> (oc,ic,KP) zero-padded, KP%4==0
__global__ void k_repack(const float* __restrict__ w, float* __restrict__ wp,
                         int KW, int KP){
  int i = blockIdx.x * 256 + threadIdx.x;
  if (i >= 1024 * KP) return;
  int k = i % KP, oi = i / KP;
  wp[i] = (k < KW) ? w[(size_t)oi * KW + k] : 0.f;
}

// conv over 32->32 channels, 64-token tile + halo in LDS, packed weights.
// thread = (tok = tid&63, grp = tid>>6) computes 8 output channels.
template<int KP, int PAD, int COFF>
__global__ void k_convK(const float* __restrict__ xb, const float* __restrict__ wp,
                        float* __restrict__ cat){
  constexpr int TC = 64;
  constexpr int RROWS = TC + KP - 1;       // data rows; row RROWS is the zero row
  __shared__ float Xs[(RROWS + 1) * 33];
  int tid = threadIdx.x;
  int G0 = blockIdx.x * TC;
  int tok = tid & 63, grp = tid >> 6;
  // stage Xs (+ zero row), float4 global reads over channels
  for (int j = tid; j < (RROWS + 1) * 8; j += 256){
    int r = j >> 3, c = (j & 7) * 4;
    float4 v = {0.f, 0.f, 0.f, 0.f};
    if (r < RROWS){
      int g = G0 - PAD + r;
      if (g >= 0 && g < TOK_) v = *(const float4*)(xb + (size_t)g * 32 + c);
    }
    float* xd = &Xs[r * 33 + c];
    xd[0] = v.x; xd[1] = v.y; xd[2] = v.z; xd[3] = v.w;
  }
  __syncthreads();
  int t = (G0 + tok) % T_;
  float acc[8] = {};
  const float* wb = wp + (size_t)(grp * 8) * 32 * KP;
  for (int q = 0; q < KP / 4; q++){
    int rs[4];
    #pragma unroll
    for (int j = 0; j < 4; j++){
      int k = q * 4 + j;
      unsigned tt = (unsigned)(t + k - PAD);
      rs[j] = (tt < (unsigned)T_) ? (tok + k) * 33 : RROWS * 33;
    }
    #pragma unroll 4
    for (int ic = 0; ic < 32; ic++){
      float x0 = Xs[rs[0] + ic], x1 = Xs[rs[1] + ic];
      float x2 = Xs[rs[2] + ic], x3 = Xs[rs[3] + ic];
      #pragma unroll
      for (int j = 0; j < 8; j++){
        float4 wv = *(const float4*)(wb + ((size_t)j * 32 + ic) * KP + q * 4);
        acc[j] += x0 * wv.x + x1 * wv.y + x2 * wv.z + x3 * wv.w;
      }
    }
  }
  int g = G0 + tok;
  if (g < TOK_){
    #pragma unroll
    for (int j = 0; j < 8; j++)
      cat[(size_t)g * 128 + COFF + grp * 8 + j] = acc[j];
  }
}

// BN stats: coalesced grid-stride, per-channel atomics into stats[0..255]
__global__ void k_bnstat(const float* __restrict__ cat, float* __restrict__ stats){
  __shared__ float sm[512];
  int tid = threadIdx.x;
  float s = 0.f, q = 0.f;
  for (int rp = blockIdx.x; rp < TOK_ / 2; rp += gridDim.x){
    float v = cat[(size_t)rp * 256 + tid];
    s += v; q += v * v;
  }
  sm[tid] = s; sm[256 + tid] = q;
  __syncthreads();
  if (tid < 128){
    atomicAdd(&stats[tid], sm[tid] + sm[tid + 128]);
    atomicAdd(&stats[128 + tid], sm[256 + tid] + sm[256 + tid + 128]);
  }
}

__global__ void k_bnact(float* __restrict__ cat, const float* __restrict__ stats,
                        const float* __restrict__ g, const float* __restrict__ b){
  int i = blockIdx.x * 256 + threadIdx.x;
  int c = i & 127;
  float mu = stats[c] * (1.f / TOK_);
  float var = stats[128 + c] * (1.f / TOK_) - mu * mu;
  float v = cat[i];
  v = (v - mu) * rsqrtf(var + 1e-5f) * g[c] + b[c];
  cat[i] = gelu_f(v);
}

__global__ void k_final(const float* __restrict__ xcat, const float* __restrict__ moe,
                        const float* __restrict__ iout, const float* __restrict__ pb,
                        float* __restrict__ out){
  size_t i = (size_t)blockIdx.x * 256 + threadIdx.x;
  int d = (int)(i & 511);
  out[i] = gelu_f(xcat[i] + moe[i] + iout[i] + pb[d]);
}

__global__ void k_loss(const float* __restrict__ gsum, float* __restrict__ o){
  if (threadIdx.x == 0){
    float l = 0;
    for (int e = 0; e < E_; e++){ float m = gsum[e] / (float)TOK_; l += m * m; }
    o[0] = (float)E_ * l;
  }
}

extern "C" void kernel_launch(void* const* d_in, const int* in_sizes, int n_in,
                              void* d_out, int out_size, void* d_ws, size_t ws_size,
                              hipStream_t stream){
  const float* x      = (const float*)d_in[0];
  const float* gamma1 = (const float*)d_in[2];
  const float* gamma2 = (const float*)d_in[3];
  const float* attn_w = (const float*)d_in[4];
  const float* attn_b = (const float*)d_in[5];
  const float* gate_w = (const float*)d_in[6];
  const float* ew1    = (const float*)d_in[7];
  const float* ew2    = (const float*)d_in[8];
  const float* bott_w = (const float*)d_in[9];
  const float* w39    = (const float*)d_in[10];
  const float* w19    = (const float*)d_in[11];
  const float* w9     = (const float*)d_in[12];
  const float* mp_w   = (const float*)d_in[13];
  const float* bn_g   = (const float*)d_in[14];
  const float* bn_b   = (const float*)d_in[15];
  const float* proj_w = (const float*)d_in[16];
  const float* proj_b = (const float*)d_in[17];
  float* out = (float*)d_out;

  float* ws = (float*)d_ws;
  size_t off = 0;
  auto alloc = [&](size_t n){ size_t o = off; off += (n + 63) & ~(size_t)63; return o; };
  size_t big = (size_t)TOK_ * H_;
  size_t xsz = (size_t)B_ * N_ * D_;
  size_t f_xs   = alloc(big > xsz ? big : xsz);   // xs, later reused as h
  size_t f_sc   = alloc(B_ * N_);
  size_t f_fl   = alloc(B_ * N_);
  size_t f_idx  = alloc(B_ * KL_);
  size_t f_xcat = alloc((size_t)TOK_ * D_);
  size_t f_xn2  = alloc((size_t)TOK_ * D_);
  size_t f_gate = alloc(TOK_ * E_);
  size_t f_gs   = alloc(64);
  size_t f_st   = alloc(256);
  size_t f_moe  = alloc((size_t)TOK_ * D_);
  size_t f_xb   = alloc((size_t)TOK_ * NF_);
  size_t f_cat  = alloc((size_t)TOK_ * 128);
  size_t f_iout = alloc((size_t)TOK_ * D_);
  size_t f_part = alloc((size_t)64 * D_);
  size_t f_wp39 = alloc(1024 * 40);
  size_t f_wp19 = alloc(1024 * 20);
  size_t f_wp9  = alloc(1024 * 12);
  (void)ws_size; (void)in_sizes; (void)n_in; (void)out_size;

  float* xs   = ws + f_xs;
  float* sc   = ws + f_sc;
  int*   fl   = (int*)(ws + f_fl);
  int*   idx  = (int*)(ws + f_idx);
  float* xcat = ws + f_xcat;
  float* xn2  = ws + f_xn2;
  float* gate = ws + f_gate;
  float* gs   = ws + f_gs;
  float* stats= ws + f_st;
  float* moe  = ws + f_moe;
  float* xb   = ws + f_xb;
  float* cat  = ws + f_cat;
  float* iout = ws + f_iout;
  float* part = ws + f_part;
  float* wp39 = ws + f_wp39;
  float* wp19 = ws + f_wp19;
  float* wp9  = ws + f_wp9;

  hipMemsetAsync(moe, 0, (size_t)TOK_ * D_ * sizeof(float), stream);
  hipMemsetAsync(gs, 0, (64 + 256) * sizeof(float), stream);   // gs + stats contiguous

  k_repack<<<(1024 * 40 + 255) / 256, 256, 0, stream>>>(w39, wp39, 39, 40);
  k_repack<<<(1024 * 20 + 255) / 256, 256, 0, stream>>>(w19, wp19, 19, 20);
  k_repack<<<(1024 * 12 + 255) / 256, 256, 0, stream>>>(w9, wp9, 9, 12);

  k_rms_score<<<B_ * N_, 256, 0, stream>>>(x, gamma1, attn_w, attn_b, xs, sc);
  k_select<<<dim3(N_ / 256, B_), 256, 0, stream>>>(sc, fl);
  k_compact<<<B_, 64, 0, stream>>>(fl, idx);
  k_gather<<<(B_ * KL_ * D_) / 256, 256, 0, stream>>>(xs, idx, xcat);
  k_extra1<<<dim3(16, B_), 256, 0, stream>>>(xs, fl, part);
  k_extra2<<<dim3(2, B_), 256, 0, stream>>>(part, xcat);
  k_rms2<<<TOK_, 256, 0, stream>>>(xcat, gamma2, xn2);
  k_gate<<<TOK_, 64, 0, stream>>>(xn2, gate_w, gate, gs);

  int mtiles = (TOK_ + 63) / 64;   // 129
  float* hbuf = xs;
  for (int e = 0; e < E_; e++){
    gemm64<1><<<dim3(H_ / 64, mtiles), 256, 0, stream>>>(
        xn2, ew1 + (size_t)e * D_ * H_, hbuf, TOK_, H_, D_, gate + e, E_);
    gemm64<2><<<dim3(D_ / 64, mtiles), 256, 0, stream>>>(
        hbuf, ew2 + (size_t)e * H_ * D_, moe, TOK_, D_, H_, nullptr, 0);
  }

  int tblocks = (TOK_ + 63) / 64;  // 129
  k_1x1<false><<<tblocks, 256, 0, stream>>>(xn2, bott_w, xb, 32, 0);
  k_1x1<true ><<<tblocks, 256, 0, stream>>>(xn2, mp_w, cat, 128, 96);
  k_convK<40, 19, 0 ><<<tblocks, 256, 0, stream>>>(xb, wp39, cat);
  k_convK<20, 9, 32><<<tblocks, 256, 0, stream>>>(xb, wp19, cat);
  k_convK<12, 4, 64><<<tblocks, 256, 0, stream>>>(xb, wp9, cat);
  k_bnstat<<<64, 256, 0, stream>>>(cat, stats);
  k_bnact<<<(TOK_ * 128) / 256, 256, 0, stream>>>(cat, stats, bn_g, bn_b);
  gemm64<0><<<dim3(D_ / 64, mtiles), 256, 0, stream>>>(
      cat, proj_w, iout, TOK_, D_, 128, nullptr, 0);
  k_final<<<((size_t)TOK_ * D_) / 256, 256, 0, stream>>>(xcat, moe, iout, proj_b, out);
  k_loss<<<1, 64, 0, stream>>>(gs, out + (size_t)TOK_ * D_);
}

// Round 3
// 1317.635 us; speedup vs baseline: 3.9725x; 2.0806x over previous
//
#include <hip/hip_runtime.h>
#include <hip/hip_bf16.h>
#include <math.h>

#define DEV __device__ __forceinline__

constexpr int B_ = 4, N_ = 4096, D_ = 512, E_ = 4, H_ = 1024, NF_ = 32;
constexpr int KL_ = 2048, T_ = KL_ + 1;          // 2049
constexpr int TOK_ = B_ * T_;                    // 8196

typedef __bf16 bf16x8 __attribute__((ext_vector_type(8)));
typedef float f32x4 __attribute__((ext_vector_type(4)));

DEV float gelu_f(float x){ return 0.5f * x * (1.0f + erff(x * 0.7071067811865475f)); }

DEV float wave_sum(float v){
  #pragma unroll
  for (int off = 32; off > 0; off >>= 1) v += __shfl_down(v, off, 64);
  return v;
}

DEV float block_sum256(float v, float* sm){
  v = wave_sum(v);
  int lane = threadIdx.x & 63, wid = threadIdx.x >> 6;
  if (lane == 0) sm[wid] = v;
  __syncthreads();
  if (threadIdx.x == 0) sm[0] = sm[0] + sm[1] + sm[2] + sm[3];
  __syncthreads();
  float r = sm[0];
  __syncthreads();
  return r;
}

// rmsnorm1 + sigmoid score + xs = x_n * score.
__global__ void k_rms_score(const float* __restrict__ x, const float* __restrict__ g,
                            const float* __restrict__ aw, const float* __restrict__ ab,
                            float* __restrict__ xs, float* __restrict__ scores){
  __shared__ float sm[4];
  int row = blockIdx.x; int tid = threadIdx.x;
  const float* xr = x + (size_t)row * D_;
  float v0 = xr[tid], v1 = xr[tid + 256];
  float ss = block_sum256(v0 * v0 + v1 * v1, sm);
  float n = fmaxf(sqrtf(ss), 1e-12f);
  float inv = 22.627416997969522f / n;   // sqrt(512)
  float xn0 = v0 * inv * g[tid], xn1 = v1 * inv * g[tid + 256];
  float z = block_sum256(xn0 * aw[tid] + xn1 * aw[tid + 256], sm) + ab[0];
  float s = 1.0f / (1.0f + expf(-z));
  float* o = xs + (size_t)row * D_;
  o[tid] = xn0 * s; o[tid + 256] = xn1 * s;
  if (tid == 0) scores[row] = s;
}

// top-k selection flags via exact rank (ties -> lower index, matches lax.top_k)
__global__ void k_select(const float* __restrict__ scores, int* __restrict__ flags){
  __shared__ float s[N_];
  int b = blockIdx.y; int tid = threadIdx.x;
  int i = blockIdx.x * 256 + tid;
  const float4* src = (const float4*)(scores + (size_t)b * N_);
  for (int j = tid; j < N_ / 4; j += 256) ((float4*)s)[j] = src[j];
  __syncthreads();
  float si = s[i];
  int cnt = 0;
  for (int j = 0; j < N_; j += 4){
    float4 v = *(const float4*)&s[j];
    cnt += (v.x > si) || (v.x == si && (j + 0) < i);
    cnt += (v.y > si) || (v.y == si && (j + 1) < i);
    cnt += (v.z > si) || (v.z == si && (j + 2) < i);
    cnt += (v.w > si) || (v.w == si && (j + 3) < i);
  }
  flags[(size_t)b * N_ + i] = (cnt < KL_) ? 1 : 0;
}

__global__ void k_compact(const int* __restrict__ flags, int* __restrict__ idx){
  int b = blockIdx.x; int lane = threadIdx.x;
  int base = 0;
  for (int chunk = 0; chunk < N_ / 64; chunk++){
    int t = chunk * 64 + lane;
    int fl = flags[(size_t)b * N_ + t];
    unsigned long long m = __ballot(fl != 0);
    int pre = __popcll(m & ((1ull << lane) - 1ull));
    if (fl) idx[(size_t)b * KL_ + base + pre] = t;
    base += __popcll(m);
  }
}

__global__ void k_gather(const float* __restrict__ xs, const int* __restrict__ idx,
                         float* __restrict__ xcat){
  size_t i = (size_t)blockIdx.x * 256 + threadIdx.x;
  int d = (int)(i & 511);
  int p = (int)((i >> 9) & (KL_ - 1));
  int b = (int)(i >> 20);
  int tok = idx[(size_t)b * KL_ + p];
  xcat[((size_t)b * T_ + p) * D_ + d] = xs[((size_t)b * N_ + tok) * D_ + d];
}

// extra row = sum of unselected xs rows: coalesced two-stage reduction
__global__ void k_extra1(const float* __restrict__ xs, const int* __restrict__ flags,
                         float* __restrict__ part){
  int b = blockIdx.y, blk = blockIdx.x;
  int tid = threadIdx.x;
  const int* fb = flags + (size_t)b * N_ + blk * 256;
  const float2* xp = (const float2*)(xs + ((size_t)b * N_ + blk * 256) * D_) + tid;
  float2 acc = {0.f, 0.f};
  for (int i = 0; i < 256; i++){
    if (!fb[i]){
      float2 v = xp[(size_t)i * 256];
      acc.x += v.x; acc.y += v.y;
    }
  }
  float* pr = part + ((size_t)(b * 16 + blk)) * D_;
  pr[tid * 2] = acc.x; pr[tid * 2 + 1] = acc.y;
}

__global__ void k_extra2(const float* __restrict__ part, float* __restrict__ xcat){
  int b = blockIdx.y; int d = blockIdx.x * 256 + threadIdx.x;
  float s = 0.f;
  for (int i = 0; i < 16; i++) s += part[((size_t)(b * 16 + i)) * D_ + d];
  xcat[((size_t)b * T_ + KL_) * D_ + d] = s;
}

// rmsnorm2 + fused gate logits/softmax. Writes xn2 (f32), xn2b (bf16), gate, gsum.
__global__ void k_rms2gate(const float* __restrict__ xc, const float* __restrict__ g,
                           const float* __restrict__ gw,
                           float* __restrict__ xn2, __hip_bfloat16* __restrict__ xn2b,
                           float* __restrict__ gate, float* __restrict__ gsum){
  __shared__ float sm[4];
  __shared__ float sg[16];
  int row = blockIdx.x; int tid = threadIdx.x;
  const float* xr = xc + (size_t)row * D_;
  float v0 = xr[tid], v1 = xr[tid + 256];
  float ss = block_sum256(v0 * v0 + v1 * v1, sm);
  float n = fmaxf(sqrtf(ss), 1e-12f);
  float inv = 22.627416997969522f / n;
  float xn0 = v0 * inv * g[tid], xn1 = v1 * inv * g[tid + 256];
  float* o = xn2 + (size_t)row * D_;
  o[tid] = xn0; o[tid + 256] = xn1;
  __hip_bfloat16* ob = xn2b + (size_t)row * D_;
  ob[tid] = __float2bfloat16(xn0); ob[tid + 256] = __float2bfloat16(xn1);
  const float4* gw4 = (const float4*)gw;
  float4 wa = gw4[tid], wb = gw4[tid + 256];
  float l0 = xn0 * wa.x + xn1 * wb.x, l1 = xn0 * wa.y + xn1 * wb.y;
  float l2 = xn0 * wa.z + xn1 * wb.z, l3 = xn0 * wa.w + xn1 * wb.w;
  l0 = wave_sum(l0); l1 = wave_sum(l1); l2 = wave_sum(l2); l3 = wave_sum(l3);
  int lane = tid & 63, wid = tid >> 6;
  if (lane == 0){ sg[wid*4+0]=l0; sg[wid*4+1]=l1; sg[wid*4+2]=l2; sg[wid*4+3]=l3; }
  __syncthreads();
  if (tid == 0){
    float a0 = sg[0]+sg[4]+sg[8]+sg[12];
    float a1 = sg[1]+sg[5]+sg[9]+sg[13];
    float a2 = sg[2]+sg[6]+sg[10]+sg[14];
    float a3 = sg[3]+sg[7]+sg[11]+sg[15];
    float m = fmaxf(fmaxf(a0, a1), fmaxf(a2, a3));
    float e0 = expf(a0-m), e1 = expf(a1-m), e2 = expf(a2-m), e3 = expf(a3-m);
    float is = 1.f / (e0+e1+e2+e3);
    float* gr = gate + (size_t)row * 4;
    gr[0]=e0*is; gr[1]=e1*is; gr[2]=e2*is; gr[3]=e3*is;
    atomicAdd(&gsum[0], e0*is); atomicAdd(&gsum[1], e1*is);
    atomicAdd(&gsum[2], e2*is); atomicAdd(&gsum[3], e3*is);
  }
}

// LDS-tiled transpose+convert: in (R x C) f32 -> out (C x R) bf16, batched over z.
__global__ void k_trb(const float* __restrict__ in, __hip_bfloat16* __restrict__ out,
                      int R, int C){
  __shared__ float t[32][33];
  int mat = blockIdx.z;
  in  += (size_t)mat * R * C;
  out += (size_t)mat * R * C;
  int c0 = blockIdx.x * 32, r0 = blockIdx.y * 32;
  int j = threadIdx.x & 31, i4 = threadIdx.x >> 5;
  #pragma unroll
  for (int k = 0; k < 4; k++){
    int i = i4 * 4 + k;
    t[i][j] = in[(size_t)(r0 + i) * C + c0 + j];
  }
  __syncthreads();
  #pragma unroll
  for (int k = 0; k < 4; k++){
    int i = i4 * 4 + k;
    out[(size_t)(c0 + i) * R + r0 + j] = __float2bfloat16(t[j][i]);
  }
}

// bf16 MFMA GEMM, B pre-transposed (Bt: N x K row-major). C = A(MxK) @ B(KxN).
// 128x128 tile, BK=32, 4 waves (2x2 of 64x64). global_load_lds width 16,
// linear LDS dest + inverse-swizzled global source (slot s^(r&3)).
// EPI 0: Cf = acc; EPI 1: Cb = bf16(gelu(acc) * gatep[row*4]); EPI 2: Cf += acc.
template<int EPI>
__launch_bounds__(256)
__global__ void gemm_bt(const __hip_bfloat16* __restrict__ A,
                        const __hip_bfloat16* __restrict__ Bt,
                        float* __restrict__ Cf, __hip_bfloat16* __restrict__ Cb,
                        int M, int N, int K, const float* __restrict__ gatep){
  __shared__ __align__(16) char smem[2][16384];   // [buf][A 8K | B 8K]
  int tid = threadIdx.x;
  int m0 = blockIdx.y * 128, n0 = blockIdx.x * 128;
  int ln = tid & 63, wid = tid >> 6;
  int wm = wid >> 1, wn = wid & 1;

  f32x4 acc[4][4] = {};

  auto stage = [&](int buf, int k0){
    #pragma unroll
    for (int c = 0; c < 2; c++){
      int ii = tid + c * 256;
      int r = ii >> 2, s = ii & 3;
      int gm = m0 + r; gm = gm < M ? gm : M - 1;
      const __hip_bfloat16* gp = A + (size_t)gm * K + (k0 + ((s ^ (r & 3)) << 3));
      __builtin_amdgcn_global_load_lds(
          (const __attribute__((address_space(1))) void*)gp,
          (__attribute__((address_space(3))) void*)&smem[buf][ii * 16], 16, 0, 0);
    }
    #pragma unroll
    for (int c = 0; c < 2; c++){
      int ii = tid + c * 256;
      int r = ii >> 2, s = ii & 3;
      const __hip_bfloat16* gp = Bt + (size_t)(n0 + r) * K + (k0 + ((s ^ (r & 3)) << 3));
      __builtin_amdgcn_global_load_lds(
          (const __attribute__((address_space(1))) void*)gp,
          (__attribute__((address_space(3))) void*)&smem[buf][8192 + ii * 16], 16, 0, 0);
    }
  };

  int nk = K >> 5;
  stage(0, 0);
  __syncthreads();
  int slotb = (((ln >> 4) ^ (ln & 3)) << 4);   // swizzled 16B slot for my kgrp
  for (int t = 0; t < nk; t++){
    int buf = t & 1;
    if (t + 1 < nk) stage(buf ^ 1, (t + 1) << 5);
    bf16x8 af[4], bfr[4];
    #pragma unroll
    for (int m = 0; m < 4; m++){
      int R = wm * 64 + m * 16 + (ln & 15);
      af[m] = *(const bf16x8*)&smem[buf][R * 64 + slotb];
    }
    #pragma unroll
    for (int n = 0; n < 4; n++){
      int R = wn * 64 + n * 16 + (ln & 15);
      bfr[n] = *(const bf16x8*)&smem[buf][8192 + R * 64 + slotb];
    }
    #pragma unroll
    for (int m = 0; m < 4; m++)
      #pragma unroll
      for (int n = 0; n < 4; n++)
        acc[m][n] = __builtin_amdgcn_mfma_f32_16x16x32_bf16(af[m], bfr[n], acc[m][n], 0, 0, 0);
    __syncthreads();
  }

  #pragma unroll
  for (int m = 0; m < 4; m++){
    int rb = m0 + wm * 64 + m * 16 + ((ln >> 4) << 2);
    #pragma unroll
    for (int n = 0; n < 4; n++){
      int col = n0 + wn * 64 + n * 16 + (ln & 15);
      #pragma unroll
      for (int r = 0; r < 4; r++){
        int row = rb + r;
        if (row < M){
          size_t ci = (size_t)row * N + col;
          float v = acc[m][n][r];
          if (EPI == 0) Cf[ci] = v;
          else if (EPI == 1) Cb[ci] = __float2bfloat16(gelu_f(v) * gatep[(size_t)row * 4]);
          else Cf[ci] += v;
        }
      }
    }
  }
}

// 1x1 conv (optionally maxpool3 input): 64-token tile, 32 out-features.
template<bool MP>
__global__ void k_1x1(const float* __restrict__ xn2, const float* __restrict__ w,
                      float* __restrict__ out, int ostride, int ooff){
  __shared__ float Xs[64 * 33];
  __shared__ float Ws[32 * 40];
  int tid = threadIdx.x;
  int G0 = blockIdx.x * 64;
  int tok = tid & 63, grp = tid >> 6;
  float acc[8] = {};
  for (int d0 = 0; d0 < D_; d0 += 32){
    for (int j = tid; j < 64 * 8; j += 256){
      int tt = j >> 3, dc = (j & 7) * 4;
      int g = G0 + tt;
      float4 v = {0.f, 0.f, 0.f, 0.f};
      if (g < TOK_){
        const float* p = xn2 + (size_t)g * D_ + d0 + dc;
        v = *(const float4*)p;
        if (MP){
          int t = g % T_;
          if (t > 0){ float4 u = *(const float4*)(p - D_);
            v.x = fmaxf(v.x, u.x); v.y = fmaxf(v.y, u.y);
            v.z = fmaxf(v.z, u.z); v.w = fmaxf(v.w, u.w); }
          if (t < T_ - 1){ float4 u = *(const float4*)(p + D_);
            v.x = fmaxf(v.x, u.x); v.y = fmaxf(v.y, u.y);
            v.z = fmaxf(v.z, u.z); v.w = fmaxf(v.w, u.w); }
        }
      }
      float* xd = &Xs[tt * 33 + dc];
      xd[0] = v.x; xd[1] = v.y; xd[2] = v.z; xd[3] = v.w;
    }
    for (int j = tid; j < 32 * 32; j += 256){
      int f = j >> 5, d = j & 31;
      Ws[d * 40 + f] = w[(size_t)f * D_ + d0 + d];
    }
    __syncthreads();
    const float* xr = &Xs[tok * 33];
    #pragma unroll 8
    for (int d = 0; d < 32; d++){
      float xv = xr[d];
      const float4* w4 = (const float4*)&Ws[d * 40 + grp * 8];
      float4 a = w4[0], b = w4[1];
      acc[0] += xv * a.x; acc[1] += xv * a.y; acc[2] += xv * a.z; acc[3] += xv * a.w;
      acc[4] += xv * b.x; acc[5] += xv * b.y; acc[6] += xv * b.z; acc[7] += xv * b.w;
    }
    __syncthreads();
  }
  int g = G0 + tok;
  if (g < TOK_){
    #pragma unroll
    for (int j = 0; j < 8; j++) out[(size_t)g * ostride + ooff + grp * 8 + j] = acc[j];
  }
}

// repack conv weight (oc,ic,KW) -> (oc,ic,KP) zero-padded, KP%4==0
__global__ void k_repack(const float* __restrict__ w, float* __restrict__ wp,
                         int KW, int KP){
  int i = blockIdx.x * 256 + threadIdx.x;
  if (i >= 1024 * KP) return;
  int k = i % KP, oi = i / KP;
  wp[i] = (k < KW) ? w[(size_t)oi * KW + k] : 0.f;
}

// conv over 32->32 channels, 64-token tile + halo in LDS, packed weights.
template<int KP, int PAD, int COFF>
__global__ void k_convK(const float* __restrict__ xb, const float* __restrict__ wp,
                        float* __restrict__ cat){
  constexpr int TC = 64;
  constexpr int RROWS = TC + KP - 1;
  __shared__ float Xs[(RROWS + 1) * 33];
  int tid = threadIdx.x;
  int G0 = blockIdx.x * TC;
  int tok = tid & 63, grp = tid >> 6;
  for (int j = tid; j < (RROWS + 1) * 8; j += 256){
    int r = j >> 3, c = (j & 7) * 4;
    float4 v = {0.f, 0.f, 0.f, 0.f};
    if (r < RROWS){
      int g = G0 - PAD + r;
      if (g >= 0 && g < TOK_) v = *(const float4*)(xb + (size_t)g * 32 + c);
    }
    float* xd = &Xs[r * 33 + c];
    xd[0] = v.x; xd[1] = v.y; xd[2] = v.z; xd[3] = v.w;
  }
  __syncthreads();
  int t = (G0 + tok) % T_;
  float acc[8] = {};
  const float* wb = wp + (size_t)(grp * 8) * 32 * KP;
  for (int q = 0; q < KP / 4; q++){
    int rs[4];
    #pragma unroll
    for (int j = 0; j < 4; j++){
      int k = q * 4 + j;
      unsigned tt = (unsigned)(t + k - PAD);
      rs[j] = (tt < (unsigned)T_) ? (tok + k) * 33 : RROWS * 33;
    }
    #pragma unroll 4
    for (int ic = 0; ic < 32; ic++){
      float x0 = Xs[rs[0] + ic], x1 = Xs[rs[1] + ic];
      float x2 = Xs[rs[2] + ic], x3 = Xs[rs[3] + ic];
      #pragma unroll
      for (int j = 0; j < 8; j++){
        float4 wv = *(const float4*)(wb + ((size_t)j * 32 + ic) * KP + q * 4);
        acc[j] += x0 * wv.x + x1 * wv.y + x2 * wv.z + x3 * wv.w;
      }
    }
  }
  int g = G0 + tok;
  if (g < TOK_){
    #pragma unroll
    for (int j = 0; j < 8; j++)
      cat[(size_t)g * 128 + COFF + grp * 8 + j] = acc[j];
  }
}

// BN stats: coalesced grid-stride, per-channel atomics into stats[0..255]
__global__ void k_bnstat(const float* __restrict__ cat, float* __restrict__ stats){
  __shared__ float sm[512];
  int tid = threadIdx.x;
  float s = 0.f, q = 0.f;
  for (int rp = blockIdx.x; rp < TOK_ / 2; rp += gridDim.x){
    float v = cat[(size_t)rp * 256 + tid];
    s += v; q += v * v;
  }
  sm[tid] = s; sm[256 + tid] = q;
  __syncthreads();
  if (tid < 128){
    atomicAdd(&stats[tid], sm[tid] + sm[tid + 128]);
    atomicAdd(&stats[128 + tid], sm[256 + tid] + sm[256 + tid + 128]);
  }
}

// BN normalize + gelu, output bf16 for the MFMA projection GEMM
__global__ void k_bnact(const float* __restrict__ cat, __hip_bfloat16* __restrict__ catb,
                        const float* __restrict__ stats,
                        const float* __restrict__ g, const float* __restrict__ b){
  int i = blockIdx.x * 256 + threadIdx.x;
  int c = i & 127;
  float mu = stats[c] * (1.f / TOK_);
  float var = stats[128 + c] * (1.f / TOK_) - mu * mu;
  float v = cat[i];
  v = (v - mu) * rsqrtf(var + 1e-5f) * g[c] + b[c];
  catb[i] = __float2bfloat16(gelu_f(v));
}

__global__ void k_final(const float* __restrict__ xcat, const float* __restrict__ moe,
                        const float* __restrict__ iout, const float* __restrict__ pb,
                        float* __restrict__ out){
  size_t i = (size_t)blockIdx.x * 256 + threadIdx.x;
  int d = (int)(i & 511);
  out[i] = gelu_f(xcat[i] + moe[i] + iout[i] + pb[d]);
}

__global__ void k_loss(const float* __restrict__ gsum, float* __restrict__ o){
  if (threadIdx.x == 0){
    float l = 0;
    for (int e = 0; e < E_; e++){ float m = gsum[e] / (float)TOK_; l += m * m; }
    o[0] = (float)E_ * l;
  }
}

extern "C" void kernel_launch(void* const* d_in, const int* in_sizes, int n_in,
                              void* d_out, int out_size, void* d_ws, size_t ws_size,
                              hipStream_t stream){
  const float* x      = (const float*)d_in[0];
  const float* gamma1 = (const float*)d_in[2];
  const float* gamma2 = (const float*)d_in[3];
  const float* attn_w = (const float*)d_in[4];
  const float* attn_b = (const float*)d_in[5];
  const float* gate_w = (const float*)d_in[6];
  const float* ew1    = (const float*)d_in[7];
  const float* ew2    = (const float*)d_in[8];
  const float* bott_w = (const float*)d_in[9];
  const float* w39    = (const float*)d_in[10];
  const float* w19    = (const float*)d_in[11];
  const float* w9     = (const float*)d_in[12];
  const float* mp_w   = (const float*)d_in[13];
  const float* bn_g   = (const float*)d_in[14];
  const float* bn_b   = (const float*)d_in[15];
  const float* proj_w = (const float*)d_in[16];
  const float* proj_b = (const float*)d_in[17];
  float* out = (float*)d_out;

  float* ws = (float*)d_ws;
  size_t off = 0;
  auto alloc = [&](size_t n){ size_t o = off; off += (n + 63) & ~(size_t)63; return o; };
  size_t f_xs   = alloc((size_t)B_ * N_ * D_);     // xs f32; later hbuf(bf16)+xn2b(bf16)
  size_t f_sc   = alloc(B_ * N_);
  size_t f_fl   = alloc(B_ * N_);
  size_t f_idx  = alloc(B_ * KL_);
  size_t f_xcat = alloc((size_t)TOK_ * D_);
  size_t f_xn2  = alloc((size_t)TOK_ * D_);
  size_t f_gate = alloc(TOK_ * E_);
  size_t f_gs   = alloc(64);
  size_t f_st   = alloc(256);
  size_t f_moe  = alloc((size_t)TOK_ * D_);
  size_t f_xb   = alloc((size_t)TOK_ * NF_);
  size_t f_cat  = alloc((size_t)TOK_ * 128);
  size_t f_iout = alloc((size_t)TOK_ * D_);        // also hosts w1b,w2b (bf16) early
  size_t f_part = alloc((size_t)64 * D_);
  size_t f_wp39 = alloc(1024 * 40);
  size_t f_wp19 = alloc(1024 * 20);
  size_t f_wp9  = alloc(1024 * 12);
  size_t f_pjb  = alloc(512 * 128 / 2 + 64);       // projb bf16 (512x128)
  size_t f_catb = alloc((size_t)TOK_ * 128 / 2 + 64); // catb bf16
  (void)ws_size; (void)in_sizes; (void)n_in; (void)out_size;

  float* xs   = ws + f_xs;
  float* sc   = ws + f_sc;
  int*   fl   = (int*)(ws + f_fl);
  int*   idx  = (int*)(ws + f_idx);
  float* xcat = ws + f_xcat;
  float* xn2  = ws + f_xn2;
  float* gate = ws + f_gate;
  float* gs   = ws + f_gs;
  float* stats= ws + f_st;
  float* moe  = ws + f_moe;
  float* xb   = ws + f_xb;
  float* cat  = ws + f_cat;
  float* iout = ws + f_iout;
  float* part = ws + f_part;
  float* wp39 = ws + f_wp39;
  float* wp19 = ws + f_wp19;
  float* wp9  = ws + f_wp9;
  __hip_bfloat16* projb = (__hip_bfloat16*)(ws + f_pjb);
  __hip_bfloat16* catb  = (__hip_bfloat16*)(ws + f_catb);
  // aliases (lifetimes disjoint):
  __hip_bfloat16* hbuf = (__hip_bfloat16*)xs;                  // TOK*H bf16
  __hip_bfloat16* xn2b = (__hip_bfloat16*)xs + (size_t)TOK_ * H_; // TOK*D bf16
  __hip_bfloat16* w1b  = (__hip_bfloat16*)iout;                // 4*H*D bf16
  __hip_bfloat16* w2b  = w1b + (size_t)E_ * H_ * D_ / 2;       // placed after w1b
  // note: w1b+w2b = 8*H*D bf16 bytes = 8.4MB <= iout region (16.8MB)

  hipMemsetAsync(gs, 0, (64 + 256) * sizeof(float), stream);   // gs + stats

  // weight preps
  k_trb<<<dim3(H_/32, D_/32, E_), 256, 0, stream>>>(ew1, w1b, D_, H_);   // -> [H][D] per e
  k_trb<<<dim3(D_/32, H_/32, E_), 256, 0, stream>>>(ew2, w2b, H_, D_);   // -> [D][H] per e
  k_trb<<<dim3(D_/32, 128/32, 1), 256, 0, stream>>>(proj_w, projb, 128, D_); // -> [512][128]
  k_repack<<<(1024 * 40 + 255) / 256, 256, 0, stream>>>(w39, wp39, 39, 40);
  k_repack<<<(1024 * 20 + 255) / 256, 256, 0, stream>>>(w19, wp19, 19, 20);
  k_repack<<<(1024 * 12 + 255) / 256, 256, 0, stream>>>(w9, wp9, 9, 12);

  k_rms_score<<<B_ * N_, 256, 0, stream>>>(x, gamma1, attn_w, attn_b, xs, sc);
  k_select<<<dim3(N_ / 256, B_), 256, 0, stream>>>(sc, fl);
  k_compact<<<B_, 64, 0, stream>>>(fl, idx);
  k_gather<<<(B_ * KL_ * D_) / 256, 256, 0, stream>>>(xs, idx, xcat);
  k_extra1<<<dim3(16, B_), 256, 0, stream>>>(xs, fl, part);
  k_extra2<<<dim3(2, B_), 256, 0, stream>>>(part, xcat);
  k_rms2gate<<<TOK_, 256, 0, stream>>>(xcat, gamma2, gate_w, xn2, xn2b, gate, gs);

  int mt = (TOK_ + 127) / 128;   // 65
  for (int e = 0; e < E_; e++){
    gemm_bt<1><<<dim3(H_/128, mt), 256, 0, stream>>>(
        xn2b, w1b + (size_t)e * H_ * D_, nullptr, hbuf, TOK_, H_, D_, gate + e);
    if (e == 0)
      gemm_bt<0><<<dim3(D_/128, mt), 256, 0, stream>>>(
          hbuf, w2b + (size_t)e * H_ * D_, moe, nullptr, TOK_, D_, H_, nullptr);
    else
      gemm_bt<2><<<dim3(D_/128, mt), 256, 0, stream>>>(
          hbuf, w2b + (size_t)e * H_ * D_, moe, nullptr, TOK_, D_, H_, nullptr);
  }

  int tblocks = (TOK_ + 63) / 64;  // 129
  k_1x1<false><<<tblocks, 256, 0, stream>>>(xn2, bott_w, xb, 32, 0);
  k_1x1<true ><<<tblocks, 256, 0, stream>>>(xn2, mp_w, cat, 128, 96);
  k_convK<40, 19, 0 ><<<tblocks, 256, 0, stream>>>(xb, wp39, cat);
  k_convK<20, 9, 32><<<tblocks, 256, 0, stream>>>(xb, wp19, cat);
  k_convK<12, 4, 64><<<tblocks, 256, 0, stream>>>(xb, wp9, cat);
  k_bnstat<<<64, 256, 0, stream>>>(cat, stats);
  k_bnact<<<(TOK_ * 128) / 256, 256, 0, stream>>>(cat, catb, stats, bn_g, bn_b);
  gemm_bt<0><<<dim3(D_/128, mt), 256, 0, stream>>>(
      catb, projb, iout, nullptr, TOK_, D_, 128, nullptr);
  k_final<<<((size_t)TOK_ * D_) / 256, 256, 0, stream>>>(xcat, moe, iout, proj_b, out);
  k_loss<<<1, 64, 0, stream>>>(gs, out + (size_t)TOK_ * D_);
}

// Round 4
// 855.179 us; speedup vs baseline: 6.1207x; 1.5408x over previous
//
#include <hip/hip_runtime.h>
#include <hip/hip_bf16.h>
#include <math.h>

#define DEV __device__ __forceinline__

constexpr int B_ = 4, N_ = 4096, D_ = 512, E_ = 4, H_ = 1024, NF_ = 32;
constexpr int KL_ = 2048, T_ = KL_ + 1;          // 2049
constexpr int TOK_ = B_ * T_;                    // 8196

typedef __bf16 bf16x8 __attribute__((ext_vector_type(8)));
typedef float f32x4 __attribute__((ext_vector_type(4)));

DEV float gelu_f(float x){ return 0.5f * x * (1.0f + erff(x * 0.7071067811865475f)); }

DEV float wave_sum(float v){
  #pragma unroll
  for (int off = 32; off > 0; off >>= 1) v += __shfl_down(v, off, 64);
  return v;
}

DEV float block_sum256(float v, float* sm){
  v = wave_sum(v);
  int lane = threadIdx.x & 63, wid = threadIdx.x >> 6;
  if (lane == 0) sm[wid] = v;
  __syncthreads();
  if (threadIdx.x == 0) sm[0] = sm[0] + sm[1] + sm[2] + sm[3];
  __syncthreads();
  float r = sm[0];
  __syncthreads();
  return r;
}

// rmsnorm1 + sigmoid score + xs = x_n * score.
__global__ void k_rms_score(const float* __restrict__ x, const float* __restrict__ g,
                            const float* __restrict__ aw, const float* __restrict__ ab,
                            float* __restrict__ xs, float* __restrict__ scores){
  __shared__ float sm[4];
  int row = blockIdx.x; int tid = threadIdx.x;
  const float* xr = x + (size_t)row * D_;
  float v0 = xr[tid], v1 = xr[tid + 256];
  float ss = block_sum256(v0 * v0 + v1 * v1, sm);
  float n = fmaxf(sqrtf(ss), 1e-12f);
  float inv = 22.627416997969522f / n;   // sqrt(512)
  float xn0 = v0 * inv * g[tid], xn1 = v1 * inv * g[tid + 256];
  float z = block_sum256(xn0 * aw[tid] + xn1 * aw[tid + 256], sm) + ab[0];
  float s = 1.0f / (1.0f + expf(-z));
  float* o = xs + (size_t)row * D_;
  o[tid] = xn0 * s; o[tid + 256] = xn1 * s;
  if (tid == 0) scores[row] = s;
}

// top-k selection flags via exact rank (ties -> lower index, matches lax.top_k)
__global__ void k_select(const float* __restrict__ scores, int* __restrict__ flags){
  __shared__ float s[N_];
  int b = blockIdx.y; int tid = threadIdx.x;
  int i = blockIdx.x * 256 + tid;
  const float4* src = (const float4*)(scores + (size_t)b * N_);
  for (int j = tid; j < N_ / 4; j += 256) ((float4*)s)[j] = src[j];
  __syncthreads();
  float si = s[i];
  int cnt = 0;
  for (int j = 0; j < N_; j += 4){
    float4 v = *(const float4*)&s[j];
    cnt += (v.x > si) || (v.x == si && (j + 0) < i);
    cnt += (v.y > si) || (v.y == si && (j + 1) < i);
    cnt += (v.z > si) || (v.z == si && (j + 2) < i);
    cnt += (v.w > si) || (v.w == si && (j + 3) < i);
  }
  flags[(size_t)b * N_ + i] = (cnt < KL_) ? 1 : 0;
}

__global__ void k_compact(const int* __restrict__ flags, int* __restrict__ idx){
  int b = blockIdx.x; int lane = threadIdx.x;
  int base = 0;
  for (int chunk = 0; chunk < N_ / 64; chunk++){
    int t = chunk * 64 + lane;
    int fl = flags[(size_t)b * N_ + t];
    unsigned long long m = __ballot(fl != 0);
    int pre = __popcll(m & ((1ull << lane) - 1ull));
    if (fl) idx[(size_t)b * KL_ + base + pre] = t;
    base += __popcll(m);
  }
}

__global__ void k_gather(const float* __restrict__ xs, const int* __restrict__ idx,
                         float* __restrict__ xcat){
  size_t i = (size_t)blockIdx.x * 256 + threadIdx.x;
  int d = (int)(i & 511);
  int p = (int)((i >> 9) & (KL_ - 1));
  int b = (int)(i >> 20);
  int tok = idx[(size_t)b * KL_ + p];
  xcat[((size_t)b * T_ + p) * D_ + d] = xs[((size_t)b * N_ + tok) * D_ + d];
}

// extra row = sum of unselected xs rows: coalesced two-stage reduction
__global__ void k_extra1(const float* __restrict__ xs, const int* __restrict__ flags,
                         float* __restrict__ part){
  int b = blockIdx.y, blk = blockIdx.x;
  int tid = threadIdx.x;
  const int* fb = flags + (size_t)b * N_ + blk * 256;
  const float2* xp = (const float2*)(xs + ((size_t)b * N_ + blk * 256) * D_) + tid;
  float2 acc = {0.f, 0.f};
  for (int i = 0; i < 256; i++){
    if (!fb[i]){
      float2 v = xp[(size_t)i * 256];
      acc.x += v.x; acc.y += v.y;
    }
  }
  float* pr = part + ((size_t)(b * 16 + blk)) * D_;
  pr[tid * 2] = acc.x; pr[tid * 2 + 1] = acc.y;
}

__global__ void k_extra2(const float* __restrict__ part, float* __restrict__ xcat){
  int b = blockIdx.y; int d = blockIdx.x * 256 + threadIdx.x;
  float s = 0.f;
  for (int i = 0; i < 16; i++) s += part[((size_t)(b * 16 + i)) * D_ + d];
  xcat[((size_t)b * T_ + KL_) * D_ + d] = s;
}

// rmsnorm2 + fused gate logits/softmax. Writes xn2 (f32), xn2b (bf16), gate.
// NO global atomics here (same-line atomic serialization was 420us in r2/r3).
__global__ void k_rms2gate(const float* __restrict__ xc, const float* __restrict__ g,
                           const float* __restrict__ gw,
                           float* __restrict__ xn2, __hip_bfloat16* __restrict__ xn2b,
                           float* __restrict__ gate){
  __shared__ float sm[4];
  __shared__ float sg[16];
  int row = blockIdx.x; int tid = threadIdx.x;
  const float* xr = xc + (size_t)row * D_;
  float v0 = xr[tid], v1 = xr[tid + 256];
  float ss = block_sum256(v0 * v0 + v1 * v1, sm);
  float n = fmaxf(sqrtf(ss), 1e-12f);
  float inv = 22.627416997969522f / n;
  float xn0 = v0 * inv * g[tid], xn1 = v1 * inv * g[tid + 256];
  float* o = xn2 + (size_t)row * D_;
  o[tid] = xn0; o[tid + 256] = xn1;
  __hip_bfloat16* ob = xn2b + (size_t)row * D_;
  ob[tid] = __float2bfloat16(xn0); ob[tid + 256] = __float2bfloat16(xn1);
  const float4* gw4 = (const float4*)gw;
  float4 wa = gw4[tid], wb = gw4[tid + 256];
  float l0 = xn0 * wa.x + xn1 * wb.x, l1 = xn0 * wa.y + xn1 * wb.y;
  float l2 = xn0 * wa.z + xn1 * wb.z, l3 = xn0 * wa.w + xn1 * wb.w;
  l0 = wave_sum(l0); l1 = wave_sum(l1); l2 = wave_sum(l2); l3 = wave_sum(l3);
  int lane = tid & 63, wid = tid >> 6;
  if (lane == 0){ sg[wid*4+0]=l0; sg[wid*4+1]=l1; sg[wid*4+2]=l2; sg[wid*4+3]=l3; }
  __syncthreads();
  if (tid == 0){
    float a0 = sg[0]+sg[4]+sg[8]+sg[12];
    float a1 = sg[1]+sg[5]+sg[9]+sg[13];
    float a2 = sg[2]+sg[6]+sg[10]+sg[14];
    float a3 = sg[3]+sg[7]+sg[11]+sg[15];
    float m = fmaxf(fmaxf(a0, a1), fmaxf(a2, a3));
    float e0 = expf(a0-m), e1 = expf(a1-m), e2 = expf(a2-m), e3 = expf(a3-m);
    float is = 1.f / (e0+e1+e2+e3);
    float* gr = gate + (size_t)row * 4;
    gr[0]=e0*is; gr[1]=e1*is; gr[2]=e2*is; gr[3]=e3*is;
  }
}

// reduce gate(TOK,4) -> gs[4]. 32 blocks, 128 spread atomics total.
__global__ void k_gsum(const float* __restrict__ gate, float* __restrict__ gs){
  __shared__ float sm[16];
  int tid = threadIdx.x;
  float4 a = {0.f, 0.f, 0.f, 0.f};
  for (int r = blockIdx.x * 256 + tid; r < TOK_; r += gridDim.x * 256){
    float4 v = *(const float4*)(gate + (size_t)r * 4);
    a.x += v.x; a.y += v.y; a.z += v.z; a.w += v.w;
  }
  a.x = wave_sum(a.x); a.y = wave_sum(a.y); a.z = wave_sum(a.z); a.w = wave_sum(a.w);
  int lane = tid & 63, wid = tid >> 6;
  if (lane == 0){ sm[wid*4]=a.x; sm[wid*4+1]=a.y; sm[wid*4+2]=a.z; sm[wid*4+3]=a.w; }
  __syncthreads();
  if (tid < 4){
    float s = sm[tid] + sm[4+tid] + sm[8+tid] + sm[12+tid];
    atomicAdd(&gs[tid], s);
  }
}

// LDS-tiled transpose+convert: in (R x C) f32 -> out (C x R) bf16, batched over z.
__global__ void k_trb(const float* __restrict__ in, __hip_bfloat16* __restrict__ out,
                      int R, int C){
  __shared__ float t[32][33];
  int mat = blockIdx.z;
  in  += (size_t)mat * R * C;
  out += (size_t)mat * R * C;
  int c0 = blockIdx.x * 32, r0 = blockIdx.y * 32;
  int j = threadIdx.x & 31, i4 = threadIdx.x >> 5;
  #pragma unroll
  for (int k = 0; k < 4; k++){
    int i = i4 * 4 + k;
    t[i][j] = in[(size_t)(r0 + i) * C + c0 + j];
  }
  __syncthreads();
  #pragma unroll
  for (int k = 0; k < 4; k++){
    int i = i4 * 4 + k;
    out[(size_t)(c0 + i) * R + r0 + j] = __float2bfloat16(t[j][i]);
  }
}

// ew2 (E,H,D) -> w2b grouped: w2b[(e>>1)*D*2048 + d*2048 + (e&1)*H + h]
__global__ void k_trb2(const float* __restrict__ in, __hip_bfloat16* __restrict__ out){
  __shared__ float t[32][33];
  int e = blockIdx.z;
  const float* ip = in + (size_t)e * H_ * D_;
  __hip_bfloat16* op = out + (size_t)(e >> 1) * D_ * 2048 + (e & 1) * H_;
  int c0 = blockIdx.x * 32, r0 = blockIdx.y * 32;   // c over D, r over H
  int j = threadIdx.x & 31, i4 = threadIdx.x >> 5;
  #pragma unroll
  for (int k = 0; k < 4; k++){
    int i = i4 * 4 + k;
    t[i][j] = ip[(size_t)(r0 + i) * D_ + c0 + j];
  }
  __syncthreads();
  #pragma unroll
  for (int k = 0; k < 4; k++){
    int i = i4 * 4 + k;
    op[(size_t)(c0 + i) * 2048 + r0 + j] = __float2bfloat16(t[j][i]);
  }
}

// bf16 MFMA GEMM, B pre-transposed (Bt: N x K row-major). C = A(MxK) @ B(KxN).
// 128x128 tile, BK=32, 4 waves. EPI 0: Cf = acc;
// EPI 1: Cb = bf16(gelu(acc) * gatep[row*4 + (col>>10)]); EPI 2: Cf += acc.
template<int EPI>
__launch_bounds__(256)
__global__ void gemm_bt(const __hip_bfloat16* __restrict__ A,
                        const __hip_bfloat16* __restrict__ Bt,
                        float* __restrict__ Cf, __hip_bfloat16* __restrict__ Cb,
                        int M, int N, int K, const float* __restrict__ gatep){
  __shared__ __align__(16) char smem[2][16384];   // [buf][A 8K | B 8K]
  int tid = threadIdx.x;
  int m0 = blockIdx.y * 128, n0 = blockIdx.x * 128;
  int ln = tid & 63, wid = tid >> 6;
  int wm = wid >> 1, wn = wid & 1;

  f32x4 acc[4][4] = {};

  auto stage = [&](int buf, int k0){
    #pragma unroll
    for (int c = 0; c < 2; c++){
      int ii = tid + c * 256;
      int r = ii >> 2, s = ii & 3;
      int gm = m0 + r; gm = gm < M ? gm : M - 1;
      const __hip_bfloat16* gp = A + (size_t)gm * K + (k0 + ((s ^ (r & 3)) << 3));
      __builtin_amdgcn_global_load_lds(
          (const __attribute__((address_space(1))) void*)gp,
          (__attribute__((address_space(3))) void*)&smem[buf][ii * 16], 16, 0, 0);
    }
    #pragma unroll
    for (int c = 0; c < 2; c++){
      int ii = tid + c * 256;
      int r = ii >> 2, s = ii & 3;
      const __hip_bfloat16* gp = Bt + (size_t)(n0 + r) * K + (k0 + ((s ^ (r & 3)) << 3));
      __builtin_amdgcn_global_load_lds(
          (const __attribute__((address_space(1))) void*)gp,
          (__attribute__((address_space(3))) void*)&smem[buf][8192 + ii * 16], 16, 0, 0);
    }
  };

  int nk = K >> 5;
  stage(0, 0);
  __syncthreads();
  int slotb = (((ln >> 4) ^ (ln & 3)) << 4);   // swizzled 16B slot for my kgrp
  for (int t = 0; t < nk; t++){
    int buf = t & 1;
    if (t + 1 < nk) stage(buf ^ 1, (t + 1) << 5);
    bf16x8 af[4], bfr[4];
    #pragma unroll
    for (int m = 0; m < 4; m++){
      int R = wm * 64 + m * 16 + (ln & 15);
      af[m] = *(const bf16x8*)&smem[buf][R * 64 + slotb];
    }
    #pragma unroll
    for (int n = 0; n < 4; n++){
      int R = wn * 64 + n * 16 + (ln & 15);
      bfr[n] = *(const bf16x8*)&smem[buf][8192 + R * 64 + slotb];
    }
    #pragma unroll
    for (int m = 0; m < 4; m++)
      #pragma unroll
      for (int n = 0; n < 4; n++)
        acc[m][n] = __builtin_amdgcn_mfma_f32_16x16x32_bf16(af[m], bfr[n], acc[m][n], 0, 0, 0);
    __syncthreads();
  }

  #pragma unroll
  for (int m = 0; m < 4; m++){
    int rb = m0 + wm * 64 + m * 16 + ((ln >> 4) << 2);
    #pragma unroll
    for (int n = 0; n < 4; n++){
      int col = n0 + wn * 64 + n * 16 + (ln & 15);
      #pragma unroll
      for (int r = 0; r < 4; r++){
        int row = rb + r;
        if (row < M){
          size_t ci = (size_t)row * N + col;
          float v = acc[m][n][r];
          if (EPI == 0) Cf[ci] = v;
          else if (EPI == 1)
            Cb[ci] = __float2bfloat16(gelu_f(v) * gatep[(size_t)row * 4 + (col >> 10)]);
          else Cf[ci] += v;
        }
      }
    }
  }
}

// 1x1 conv (optionally maxpool3 input): 64-token tile, 32 out-features.
template<bool MP>
__global__ void k_1x1(const float* __restrict__ xn2, const float* __restrict__ w,
                      float* __restrict__ out, int ostride, int ooff){
  __shared__ float Xs[64 * 33];
  __shared__ float Ws[32 * 40];
  int tid = threadIdx.x;
  int G0 = blockIdx.x * 64;
  int tok = tid & 63, grp = tid >> 6;
  float acc[8] = {};
  for (int d0 = 0; d0 < D_; d0 += 32){
    for (int j = tid; j < 64 * 8; j += 256){
      int tt = j >> 3, dc = (j & 7) * 4;
      int g = G0 + tt;
      float4 v = {0.f, 0.f, 0.f, 0.f};
      if (g < TOK_){
        const float* p = xn2 + (size_t)g * D_ + d0 + dc;
        v = *(const float4*)p;
        if (MP){
          int t = g % T_;
          if (t > 0){ float4 u = *(const float4*)(p - D_);
            v.x = fmaxf(v.x, u.x); v.y = fmaxf(v.y, u.y);
            v.z = fmaxf(v.z, u.z); v.w = fmaxf(v.w, u.w); }
          if (t < T_ - 1){ float4 u = *(const float4*)(p + D_);
            v.x = fmaxf(v.x, u.x); v.y = fmaxf(v.y, u.y);
            v.z = fmaxf(v.z, u.z); v.w = fmaxf(v.w, u.w); }
        }
      }
      float* xd = &Xs[tt * 33 + dc];
      xd[0] = v.x; xd[1] = v.y; xd[2] = v.z; xd[3] = v.w;
    }
    for (int j = tid; j < 32 * 32; j += 256){
      int f = j >> 5, d = j & 31;
      Ws[d * 40 + f] = w[(size_t)f * D_ + d0 + d];
    }
    __syncthreads();
    const float* xr = &Xs[tok * 33];
    #pragma unroll 8
    for (int d = 0; d < 32; d++){
      float xv = xr[d];
      const float4* w4 = (const float4*)&Ws[d * 40 + grp * 8];
      float4 a = w4[0], b = w4[1];
      acc[0] += xv * a.x; acc[1] += xv * a.y; acc[2] += xv * a.z; acc[3] += xv * a.w;
      acc[4] += xv * b.x; acc[5] += xv * b.y; acc[6] += xv * b.z; acc[7] += xv * b.w;
    }
    __syncthreads();
  }
  int g = G0 + tok;
  if (g < TOK_){
    #pragma unroll
    for (int j = 0; j < 8; j++) out[(size_t)g * ostride + ooff + grp * 8 + j] = acc[j];
  }
}

// repack conv weight (oc,ic,KW) -> (oc,ic,KP) zero-padded, KP%4==0
__global__ void k_repack(const float* __restrict__ w, float* __restrict__ wp,
                         int KW, int KP){
  int i = blockIdx.x * 256 + threadIdx.x;
  if (i >= 1024 * KP) return;
  int k = i % KP, oi = i / KP;
  wp[i] = (k < KW) ? w[(size_t)oi * KW + k] : 0.f;
}

// conv over 32->32 channels, 64-token tile + halo in LDS, packed weights.
template<int KP, int PAD, int COFF>
__global__ void k_convK(const float* __restrict__ xb, const float* __restrict__ wp,
                        float* __restrict__ cat){
  constexpr int TC = 64;
  constexpr int RROWS = TC + KP - 1;
  __shared__ float Xs[(RROWS + 1) * 33];
  int tid = threadIdx.x;
  int G0 = blockIdx.x * TC;
  int tok = tid & 63, grp = tid >> 6;
  for (int j = tid; j < (RROWS + 1) * 8; j += 256){
    int r = j >> 3, c = (j & 7) * 4;
    float4 v = {0.f, 0.f, 0.f, 0.f};
    if (r < RROWS){
      int g = G0 - PAD + r;
      if (g >= 0 && g < TOK_) v = *(const float4*)(xb + (size_t)g * 32 + c);
    }
    float* xd = &Xs[r * 33 + c];
    xd[0] = v.x; xd[1] = v.y; xd[2] = v.z; xd[3] = v.w;
  }
  __syncthreads();
  int t = (G0 + tok) % T_;
  float acc[8] = {};
  const float* wb = wp + (size_t)(grp * 8) * 32 * KP;
  for (int q = 0; q < KP / 4; q++){
    int rs[4];
    #pragma unroll
    for (int j = 0; j < 4; j++){
      int k = q * 4 + j;
      unsigned tt = (unsigned)(t + k - PAD);
      rs[j] = (tt < (unsigned)T_) ? (tok + k) * 33 : RROWS * 33;
    }
    #pragma unroll 4
    for (int ic = 0; ic < 32; ic++){
      float x0 = Xs[rs[0] + ic], x1 = Xs[rs[1] + ic];
      float x2 = Xs[rs[2] + ic], x3 = Xs[rs[3] + ic];
      #pragma unroll
      for (int j = 0; j < 8; j++){
        float4 wv = *(const float4*)(wb + ((size_t)j * 32 + ic) * KP + q * 4);
        acc[j] += x0 * wv.x + x1 * wv.y + x2 * wv.z + x3 * wv.w;
      }
    }
  }
  int g = G0 + tok;
  if (g < TOK_){
    #pragma unroll
    for (int j = 0; j < 8; j++)
      cat[(size_t)g * 128 + COFF + grp * 8 + j] = acc[j];
  }
}

// BN stats: coalesced grid-stride, per-channel atomics into stats[0..255]
__global__ void k_bnstat(const float* __restrict__ cat, float* __restrict__ stats){
  __shared__ float sm[512];
  int tid = threadIdx.x;
  float s = 0.f, q = 0.f;
  for (int rp = blockIdx.x; rp < TOK_ / 2; rp += gridDim.x){
    float v = cat[(size_t)rp * 256 + tid];
    s += v; q += v * v;
  }
  sm[tid] = s; sm[256 + tid] = q;
  __syncthreads();
  if (tid < 128){
    atomicAdd(&stats[tid], sm[tid] + sm[tid + 128]);
    atomicAdd(&stats[128 + tid], sm[256 + tid] + sm[256 + tid + 128]);
  }
}

// BN normalize + gelu, output bf16 for the MFMA projection GEMM
__global__ void k_bnact(const float* __restrict__ cat, __hip_bfloat16* __restrict__ catb,
                        const float* __restrict__ stats,
                        const float* __restrict__ g, const float* __restrict__ b){
  int i = blockIdx.x * 256 + threadIdx.x;
  int c = i & 127;
  float mu = stats[c] * (1.f / TOK_);
  float var = stats[128 + c] * (1.f / TOK_) - mu * mu;
  float v = cat[i];
  v = (v - mu) * rsqrtf(var + 1e-5f) * g[c] + b[c];
  catb[i] = __float2bfloat16(gelu_f(v));
}

__global__ void k_final(const float* __restrict__ xcat, const float* __restrict__ moe,
                        const float* __restrict__ iout, const float* __restrict__ pb,
                        float* __restrict__ out){
  size_t i = (size_t)blockIdx.x * 256 + threadIdx.x;
  int d = (int)(i & 511);
  out[i] = gelu_f(xcat[i] + moe[i] + iout[i] + pb[d]);
}

__global__ void k_loss(const float* __restrict__ gsum, float* __restrict__ o){
  if (threadIdx.x == 0){
    float l = 0;
    for (int e = 0; e < E_; e++){ float m = gsum[e] / (float)TOK_; l += m * m; }
    o[0] = (float)E_ * l;
  }
}

extern "C" void kernel_launch(void* const* d_in, const int* in_sizes, int n_in,
                              void* d_out, int out_size, void* d_ws, size_t ws_size,
                              hipStream_t stream){
  const float* x      = (const float*)d_in[0];
  const float* gamma1 = (const float*)d_in[2];
  const float* gamma2 = (const float*)d_in[3];
  const float* attn_w = (const float*)d_in[4];
  const float* attn_b = (const float*)d_in[5];
  const float* gate_w = (const float*)d_in[6];
  const float* ew1    = (const float*)d_in[7];
  const float* ew2    = (const float*)d_in[8];
  const float* bott_w = (const float*)d_in[9];
  const float* w39    = (const float*)d_in[10];
  const float* w19    = (const float*)d_in[11];
  const float* w9     = (const float*)d_in[12];
  const float* mp_w   = (const float*)d_in[13];
  const float* bn_g   = (const float*)d_in[14];
  const float* bn_b   = (const float*)d_in[15];
  const float* proj_w = (const float*)d_in[16];
  const float* proj_b = (const float*)d_in[17];
  float* out = (float*)d_out;

  float* ws = (float*)d_ws;
  size_t off = 0;
  auto alloc = [&](size_t n){ size_t o = off; off += (n + 63) & ~(size_t)63; return o; };
  // xs region also hosts hbuf (TOK x 2048 bf16 = 8,392,704 f32-equivalents)
  size_t f_xs   = alloc(8392704);
  size_t f_sc   = alloc(B_ * N_);
  size_t f_fl   = alloc(B_ * N_);
  size_t f_idx  = alloc(B_ * KL_);
  size_t f_xcat = alloc((size_t)TOK_ * D_);
  size_t f_xn2  = alloc((size_t)TOK_ * D_);
  size_t f_gate = alloc(TOK_ * E_);
  size_t f_gs   = alloc(64);
  size_t f_st   = alloc(256);
  size_t f_moe  = alloc((size_t)TOK_ * D_);
  size_t f_xb   = alloc((size_t)TOK_ * NF_);
  size_t f_cat  = alloc((size_t)TOK_ * 128);
  size_t f_iout = alloc((size_t)TOK_ * D_);        // hosts w1b,w2b,xn2b (bf16) early
  size_t f_part = alloc((size_t)64 * D_);
  size_t f_wp39 = alloc(1024 * 40);
  size_t f_wp19 = alloc(1024 * 20);
  size_t f_wp9  = alloc(1024 * 12);
  size_t f_pjb  = alloc(512 * 128 / 2 + 64);       // projb bf16 (512x128)
  size_t f_catb = alloc((size_t)TOK_ * 128 / 2 + 64); // catb bf16
  (void)ws_size; (void)in_sizes; (void)n_in; (void)out_size;

  float* xs   = ws + f_xs;
  float* sc   = ws + f_sc;
  int*   fl   = (int*)(ws + f_fl);
  int*   idx  = (int*)(ws + f_idx);
  float* xcat = ws + f_xcat;
  float* xn2  = ws + f_xn2;
  float* gate = ws + f_gate;
  float* gs   = ws + f_gs;
  float* stats= ws + f_st;
  float* moe  = ws + f_moe;
  float* xb   = ws + f_xb;
  float* cat  = ws + f_cat;
  float* iout = ws + f_iout;
  float* part = ws + f_part;
  float* wp39 = ws + f_wp39;
  float* wp19 = ws + f_wp19;
  float* wp9  = ws + f_wp9;
  __hip_bfloat16* projb = (__hip_bfloat16*)(ws + f_pjb);
  __hip_bfloat16* catb  = (__hip_bfloat16*)(ws + f_catb);
  // aliases (lifetimes disjoint):
  __hip_bfloat16* hbuf = (__hip_bfloat16*)xs;              // TOK x 2048 bf16 (per group)
  __hip_bfloat16* w1b  = (__hip_bfloat16*)iout;            // [e][h][d]  4.2MB
  __hip_bfloat16* w2b  = w1b + (size_t)E_ * D_ * H_;       // grouped [g][d][2048]  4.2MB
  __hip_bfloat16* xn2b = w2b + (size_t)E_ * D_ * H_;       // TOK x D bf16  8.4MB
  // w1b+w2b+xn2b = 16.78MB <= iout region (16.79MB); iout written only by proj gemm later

  hipMemsetAsync(gs, 0, (64 + 256) * sizeof(float), stream);   // gs + stats

  // weight preps
  k_trb<<<dim3(H_/32, D_/32, E_), 256, 0, stream>>>(ew1, w1b, D_, H_);   // -> [e][H][D]
  k_trb2<<<dim3(D_/32, H_/32, E_), 256, 0, stream>>>(ew2, w2b);          // -> [g][D][2048]
  k_trb<<<dim3(D_/32, 128/32, 1), 256, 0, stream>>>(proj_w, projb, 128, D_); // -> [512][128]
  k_repack<<<(1024 * 40 + 255) / 256, 256, 0, stream>>>(w39, wp39, 39, 40);
  k_repack<<<(1024 * 20 + 255) / 256, 256, 0, stream>>>(w19, wp19, 19, 20);
  k_repack<<<(1024 * 12 + 255) / 256, 256, 0, stream>>>(w9, wp9, 9, 12);

  k_rms_score<<<B_ * N_, 256, 0, stream>>>(x, gamma1, attn_w, attn_b, xs, sc);
  k_select<<<dim3(N_ / 256, B_), 256, 0, stream>>>(sc, fl);
  k_compact<<<B_, 64, 0, stream>>>(fl, idx);
  k_gather<<<(B_ * KL_ * D_) / 256, 256, 0, stream>>>(xs, idx, xcat);
  k_extra1<<<dim3(16, B_), 256, 0, stream>>>(xs, fl, part);
  k_extra2<<<dim3(2, B_), 256, 0, stream>>>(part, xcat);
  k_rms2gate<<<TOK_, 256, 0, stream>>>(xcat, gamma2, gate_w, xn2, xn2b, gate);
  k_gsum<<<32, 256, 0, stream>>>(gate, gs);

  int mt = (TOK_ + 127) / 128;   // 65
  // group 0: experts {0,1}; group 1: experts {2,3}
  gemm_bt<1><<<dim3(2048/128, mt), 256, 0, stream>>>(
      xn2b, w1b, nullptr, hbuf, TOK_, 2048, D_, gate);
  gemm_bt<0><<<dim3(D_/128, mt), 256, 0, stream>>>(
      hbuf, w2b, moe, nullptr, TOK_, D_, 2048, nullptr);
  gemm_bt<1><<<dim3(2048/128, mt), 256, 0, stream>>>(
      xn2b, w1b + (size_t)2 * H_ * D_, nullptr, hbuf, TOK_, 2048, D_, gate + 2);
  gemm_bt<2><<<dim3(D_/128, mt), 256, 0, stream>>>(
      hbuf, w2b + (size_t)D_ * 2048, moe, nullptr, TOK_, D_, 2048, nullptr);

  int tblocks = (TOK_ + 63) / 64;  // 129
  k_1x1<false><<<tblocks, 256, 0, stream>>>(xn2, bott_w, xb, 32, 0);
  k_1x1<true ><<<tblocks, 256, 0, stream>>>(xn2, mp_w, cat, 128, 96);
  k_convK<40, 19, 0 ><<<tblocks, 256, 0, stream>>>(xb, wp39, cat);
  k_convK<20, 9, 32><<<tblocks, 256, 0, stream>>>(xb, wp19, cat);
  k_convK<12, 4, 64><<<tblocks, 256, 0, stream>>>(xb, wp9, cat);
  k_bnstat<<<64, 256, 0, stream>>>(cat, stats);
  k_bnact<<<(TOK_ * 128) / 256, 256, 0, stream>>>(cat, catb, stats, bn_g, bn_b);
  gemm_bt<0><<<dim3(D_/128, mt), 256, 0, stream>>>(
      catb, projb, iout, nullptr, TOK_, D_, 128, nullptr);
  k_final<<<((size_t)TOK_ * D_) / 256, 256, 0, stream>>>(xcat, moe, iout, proj_b, out);
  k_loss<<<1, 64, 0, stream>>>(gs, out + (size_t)TOK_ * D_);
}

// Round 5
// 634.657 us; speedup vs baseline: 8.2474x; 1.3475x over previous
//
#include <hip/hip_runtime.h>
#include <hip/hip_bf16.h>
#include <math.h>

#define DEV __device__ __forceinline__

constexpr int B_ = 4, N_ = 4096, D_ = 512, E_ = 4, H_ = 1024, NF_ = 32;
constexpr int KL_ = 2048, T_ = KL_ + 1;          // 2049
constexpr int TOK_ = B_ * T_;                    // 8196

typedef __bf16 bf16x8 __attribute__((ext_vector_type(8)));
typedef float f32x4 __attribute__((ext_vector_type(4)));

DEV float gelu_f(float x){ return 0.5f * x * (1.0f + erff(x * 0.7071067811865475f)); }

DEV float wave_sum(float v){
  #pragma unroll
  for (int off = 32; off > 0; off >>= 1) v += __shfl_down(v, off, 64);
  return v;
}

DEV float block_sum256(float v, float* sm){
  v = wave_sum(v);
  int lane = threadIdx.x & 63, wid = threadIdx.x >> 6;
  if (lane == 0) sm[wid] = v;
  __syncthreads();
  if (threadIdx.x == 0) sm[0] = sm[0] + sm[1] + sm[2] + sm[3];
  __syncthreads();
  float r = sm[0];
  __syncthreads();
  return r;
}

// rmsnorm1 + sigmoid score + xs = x_n * score.
__global__ void k_rms_score(const float* __restrict__ x, const float* __restrict__ g,
                            const float* __restrict__ aw, const float* __restrict__ ab,
                            float* __restrict__ xs, float* __restrict__ scores){
  __shared__ float sm[4];
  int row = blockIdx.x; int tid = threadIdx.x;
  const float* xr = x + (size_t)row * D_;
  float v0 = xr[tid], v1 = xr[tid + 256];
  float ss = block_sum256(v0 * v0 + v1 * v1, sm);
  float n = fmaxf(sqrtf(ss), 1e-12f);
  float inv = 22.627416997969522f / n;   // sqrt(512)
  float xn0 = v0 * inv * g[tid], xn1 = v1 * inv * g[tid + 256];
  float z = block_sum256(xn0 * aw[tid] + xn1 * aw[tid + 256], sm) + ab[0];
  float s = 1.0f / (1.0f + expf(-z));
  float* o = xs + (size_t)row * D_;
  o[tid] = xn0 * s; o[tid + 256] = xn1 * s;
  if (tid == 0) scores[row] = s;
}

// top-k selection flags via exact rank (ties -> lower index, matches lax.top_k)
__global__ void k_select(const float* __restrict__ scores, int* __restrict__ flags){
  __shared__ float s[N_];
  int b = blockIdx.y; int tid = threadIdx.x;
  int i = blockIdx.x * 256 + tid;
  const float4* src = (const float4*)(scores + (size_t)b * N_);
  for (int j = tid; j < N_ / 4; j += 256) ((float4*)s)[j] = src[j];
  __syncthreads();
  float si = s[i];
  int cnt = 0;
  for (int j = 0; j < N_; j += 4){
    float4 v = *(const float4*)&s[j];
    cnt += (v.x > si) || (v.x == si && (j + 0) < i);
    cnt += (v.y > si) || (v.y == si && (j + 1) < i);
    cnt += (v.z > si) || (v.z == si && (j + 2) < i);
    cnt += (v.w > si) || (v.w == si && (j + 3) < i);
  }
  flags[(size_t)b * N_ + i] = (cnt < KL_) ? 1 : 0;
}

__global__ void k_compact(const int* __restrict__ flags, int* __restrict__ idx){
  int b = blockIdx.x; int lane = threadIdx.x;
  int base = 0;
  for (int chunk = 0; chunk < N_ / 64; chunk++){
    int t = chunk * 64 + lane;
    int fl = flags[(size_t)b * N_ + t];
    unsigned long long m = __ballot(fl != 0);
    int pre = __popcll(m & ((1ull << lane) - 1ull));
    if (fl) idx[(size_t)b * KL_ + base + pre] = t;
    base += __popcll(m);
  }
}

__global__ void k_gather(const float* __restrict__ xs, const int* __restrict__ idx,
                         float* __restrict__ xcat){
  size_t i = (size_t)blockIdx.x * 256 + threadIdx.x;
  int d = (int)(i & 511);
  int p = (int)((i >> 9) & (KL_ - 1));
  int b = (int)(i >> 20);
  int tok = idx[(size_t)b * KL_ + p];
  xcat[((size_t)b * T_ + p) * D_ + d] = xs[((size_t)b * N_ + tok) * D_ + d];
}

// extra row = sum of unselected xs rows: coalesced two-stage reduction
__global__ void k_extra1(const float* __restrict__ xs, const int* __restrict__ flags,
                         float* __restrict__ part){
  int b = blockIdx.y, blk = blockIdx.x;
  int tid = threadIdx.x;
  const int* fb = flags + (size_t)b * N_ + blk * 256;
  const float2* xp = (const float2*)(xs + ((size_t)b * N_ + blk * 256) * D_) + tid;
  float2 acc = {0.f, 0.f};
  for (int i = 0; i < 256; i++){
    if (!fb[i]){
      float2 v = xp[(size_t)i * 256];
      acc.x += v.x; acc.y += v.y;
    }
  }
  float* pr = part + ((size_t)(b * 16 + blk)) * D_;
  pr[tid * 2] = acc.x; pr[tid * 2 + 1] = acc.y;
}

__global__ void k_extra2(const float* __restrict__ part, float* __restrict__ xcat){
  int b = blockIdx.y; int d = blockIdx.x * 256 + threadIdx.x;
  float s = 0.f;
  for (int i = 0; i < 16; i++) s += part[((size_t)(b * 16 + i)) * D_ + d];
  xcat[((size_t)b * T_ + KL_) * D_ + d] = s;
}

// rmsnorm2 + fused gate logits/softmax. Writes xn2 (f32), xn2b (bf16), gate.
__global__ void k_rms2gate(const float* __restrict__ xc, const float* __restrict__ g,
                           const float* __restrict__ gw,
                           float* __restrict__ xn2, __hip_bfloat16* __restrict__ xn2b,
                           float* __restrict__ gate){
  __shared__ float sm[4];
  __shared__ float sg[16];
  int row = blockIdx.x; int tid = threadIdx.x;
  const float* xr = xc + (size_t)row * D_;
  float v0 = xr[tid], v1 = xr[tid + 256];
  float ss = block_sum256(v0 * v0 + v1 * v1, sm);
  float n = fmaxf(sqrtf(ss), 1e-12f);
  float inv = 22.627416997969522f / n;
  float xn0 = v0 * inv * g[tid], xn1 = v1 * inv * g[tid + 256];
  float* o = xn2 + (size_t)row * D_;
  o[tid] = xn0; o[tid + 256] = xn1;
  __hip_bfloat16* ob = xn2b + (size_t)row * D_;
  ob[tid] = __float2bfloat16(xn0); ob[tid + 256] = __float2bfloat16(xn1);
  const float4* gw4 = (const float4*)gw;
  float4 wa = gw4[tid], wb = gw4[tid + 256];
  float l0 = xn0 * wa.x + xn1 * wb.x, l1 = xn0 * wa.y + xn1 * wb.y;
  float l2 = xn0 * wa.z + xn1 * wb.z, l3 = xn0 * wa.w + xn1 * wb.w;
  l0 = wave_sum(l0); l1 = wave_sum(l1); l2 = wave_sum(l2); l3 = wave_sum(l3);
  int lane = tid & 63, wid = tid >> 6;
  if (lane == 0){ sg[wid*4+0]=l0; sg[wid*4+1]=l1; sg[wid*4+2]=l2; sg[wid*4+3]=l3; }
  __syncthreads();
  if (tid == 0){
    float a0 = sg[0]+sg[4]+sg[8]+sg[12];
    float a1 = sg[1]+sg[5]+sg[9]+sg[13];
    float a2 = sg[2]+sg[6]+sg[10]+sg[14];
    float a3 = sg[3]+sg[7]+sg[11]+sg[15];
    float m = fmaxf(fmaxf(a0, a1), fmaxf(a2, a3));
    float e0 = expf(a0-m), e1 = expf(a1-m), e2 = expf(a2-m), e3 = expf(a3-m);
    float is = 1.f / (e0+e1+e2+e3);
    float* gr = gate + (size_t)row * 4;
    gr[0]=e0*is; gr[1]=e1*is; gr[2]=e2*is; gr[3]=e3*is;
  }
}

// reduce gate(TOK,4) -> gs[4]. 32 blocks, 128 spread atomics total.
__global__ void k_gsum(const float* __restrict__ gate, float* __restrict__ gs){
  __shared__ float sm[16];
  int tid = threadIdx.x;
  float4 a = {0.f, 0.f, 0.f, 0.f};
  for (int r = blockIdx.x * 256 + tid; r < TOK_; r += gridDim.x * 256){
    float4 v = *(const float4*)(gate + (size_t)r * 4);
    a.x += v.x; a.y += v.y; a.z += v.z; a.w += v.w;
  }
  a.x = wave_sum(a.x); a.y = wave_sum(a.y); a.z = wave_sum(a.z); a.w = wave_sum(a.w);
  int lane = tid & 63, wid = tid >> 6;
  if (lane == 0){ sm[wid*4]=a.x; sm[wid*4+1]=a.y; sm[wid*4+2]=a.z; sm[wid*4+3]=a.w; }
  __syncthreads();
  if (tid < 4){
    float s = sm[tid] + sm[4+tid] + sm[8+tid] + sm[12+tid];
    atomicAdd(&gs[tid], s);
  }
}

// LDS-tiled transpose+convert: in (R x C) f32 -> out (C x R) bf16, batched over z.
__global__ void k_trb(const float* __restrict__ in, __hip_bfloat16* __restrict__ out,
                      int R, int C){
  __shared__ float t[32][33];
  int mat = blockIdx.z;
  in  += (size_t)mat * R * C;
  out += (size_t)mat * R * C;
  int c0 = blockIdx.x * 32, r0 = blockIdx.y * 32;
  int j = threadIdx.x & 31, i4 = threadIdx.x >> 5;
  #pragma unroll
  for (int k = 0; k < 4; k++){
    int i = i4 * 4 + k;
    t[i][j] = in[(size_t)(r0 + i) * C + c0 + j];
  }
  __syncthreads();
  #pragma unroll
  for (int k = 0; k < 4; k++){
    int i = i4 * 4 + k;
    out[(size_t)(c0 + i) * R + r0 + j] = __float2bfloat16(t[j][i]);
  }
}

// ew2 (E,H,D) -> w2b grouped: w2b[(e>>1)*D*2048 + d*2048 + (e&1)*H + h]
__global__ void k_trb2(const float* __restrict__ in, __hip_bfloat16* __restrict__ out){
  __shared__ float t[32][33];
  int e = blockIdx.z;
  const float* ip = in + (size_t)e * H_ * D_;
  __hip_bfloat16* op = out + (size_t)(e >> 1) * D_ * 2048 + (e & 1) * H_;
  int c0 = blockIdx.x * 32, r0 = blockIdx.y * 32;   // c over D, r over H
  int j = threadIdx.x & 31, i4 = threadIdx.x >> 5;
  #pragma unroll
  for (int k = 0; k < 4; k++){
    int i = i4 * 4 + k;
    t[i][j] = ip[(size_t)(r0 + i) * D_ + c0 + j];
  }
  __syncthreads();
  #pragma unroll
  for (int k = 0; k < 4; k++){
    int i = i4 * 4 + k;
    op[(size_t)(c0 + i) * 2048 + r0 + j] = __float2bfloat16(t[j][i]);
  }
}

// bf16 MFMA GEMM, B pre-transposed (Bt: N x K row-major). C = A(MxK) @ B(KxN).
// 128x128 tile, BK=32, 4 waves. EPI 0: Cf = acc;
// EPI 1: Cb = bf16(gelu(acc) * gatep[row*4 + (col>>10)]); EPI 2: Cf += acc.
template<int EPI>
__launch_bounds__(256)
__global__ void gemm_bt(const __hip_bfloat16* __restrict__ A,
                        const __hip_bfloat16* __restrict__ Bt,
                        float* __restrict__ Cf, __hip_bfloat16* __restrict__ Cb,
                        int M, int N, int K, const float* __restrict__ gatep){
  __shared__ __align__(16) char smem[2][16384];   // [buf][A 8K | B 8K]
  int tid = threadIdx.x;
  int m0 = blockIdx.y * 128, n0 = blockIdx.x * 128;
  int ln = tid & 63, wid = tid >> 6;
  int wm = wid >> 1, wn = wid & 1;

  f32x4 acc[4][4] = {};

  auto stage = [&](int buf, int k0){
    #pragma unroll
    for (int c = 0; c < 2; c++){
      int ii = tid + c * 256;
      int r = ii >> 2, s = ii & 3;
      int gm = m0 + r; gm = gm < M ? gm : M - 1;
      const __hip_bfloat16* gp = A + (size_t)gm * K + (k0 + ((s ^ (r & 3)) << 3));
      __builtin_amdgcn_global_load_lds(
          (const __attribute__((address_space(1))) void*)gp,
          (__attribute__((address_space(3))) void*)&smem[buf][ii * 16], 16, 0, 0);
    }
    #pragma unroll
    for (int c = 0; c < 2; c++){
      int ii = tid + c * 256;
      int r = ii >> 2, s = ii & 3;
      const __hip_bfloat16* gp = Bt + (size_t)(n0 + r) * K + (k0 + ((s ^ (r & 3)) << 3));
      __builtin_amdgcn_global_load_lds(
          (const __attribute__((address_space(1))) void*)gp,
          (__attribute__((address_space(3))) void*)&smem[buf][8192 + ii * 16], 16, 0, 0);
    }
  };

  int nk = K >> 5;
  stage(0, 0);
  __syncthreads();
  int slotb = (((ln >> 4) ^ (ln & 3)) << 4);   // swizzled 16B slot for my kgrp
  for (int t = 0; t < nk; t++){
    int buf = t & 1;
    if (t + 1 < nk) stage(buf ^ 1, (t + 1) << 5);
    bf16x8 af[4], bfr[4];
    #pragma unroll
    for (int m = 0; m < 4; m++){
      int R = wm * 64 + m * 16 + (ln & 15);
      af[m] = *(const bf16x8*)&smem[buf][R * 64 + slotb];
    }
    #pragma unroll
    for (int n = 0; n < 4; n++){
      int R = wn * 64 + n * 16 + (ln & 15);
      bfr[n] = *(const bf16x8*)&smem[buf][8192 + R * 64 + slotb];
    }
    #pragma unroll
    for (int m = 0; m < 4; m++)
      #pragma unroll
      for (int n = 0; n < 4; n++)
        acc[m][n] = __builtin_amdgcn_mfma_f32_16x16x32_bf16(af[m], bfr[n], acc[m][n], 0, 0, 0);
    __syncthreads();
  }

  #pragma unroll
  for (int m = 0; m < 4; m++){
    int rb = m0 + wm * 64 + m * 16 + ((ln >> 4) << 2);
    #pragma unroll
    for (int n = 0; n < 4; n++){
      int col = n0 + wn * 64 + n * 16 + (ln & 15);
      #pragma unroll
      for (int r = 0; r < 4; r++){
        int row = rb + r;
        if (row < M){
          size_t ci = (size_t)row * N + col;
          float v = acc[m][n][r];
          if (EPI == 0) Cf[ci] = v;
          else if (EPI == 1)
            Cb[ci] = __float2bfloat16(gelu_f(v) * gatep[(size_t)row * 4 + (col >> 10)]);
          else Cf[ci] += v;
        }
      }
    }
  }
}

// fused 1x1 convs: blockIdx.y=0 -> bott_w -> xb; y=1 -> mp_w (maxpool3 input) -> cat.
// TC=32 tokens/block, 256 thr = 32 tok x 8 grp, 4 feats each.
__global__ void k_1x1F(const float* __restrict__ xn2, const float* __restrict__ bw,
                       const float* __restrict__ mw,
                       float* __restrict__ xb, float* __restrict__ cat){
  __shared__ float Xs[32 * 33];
  __shared__ float Ws[32 * 36];
  int type = blockIdx.y;
  const float* w = type == 0 ? bw : mw;
  int tid = threadIdx.x;
  int G0 = blockIdx.x * 32;
  int tok = tid & 31, grp = tid >> 5;
  float acc[4] = {};
  for (int d0 = 0; d0 < D_; d0 += 32){
    {
      int tt = tid >> 3, dc = (tid & 7) * 4;
      int g = G0 + tt;
      float4 v = {0.f, 0.f, 0.f, 0.f};
      if (g < TOK_){
        const float* p = xn2 + (size_t)g * D_ + d0 + dc;
        v = *(const float4*)p;
        if (type == 1){
          int t = g % T_;
          if (t > 0){ float4 u = *(const float4*)(p - D_);
            v.x = fmaxf(v.x, u.x); v.y = fmaxf(v.y, u.y);
            v.z = fmaxf(v.z, u.z); v.w = fmaxf(v.w, u.w); }
          if (t < T_ - 1){ float4 u = *(const float4*)(p + D_);
            v.x = fmaxf(v.x, u.x); v.y = fmaxf(v.y, u.y);
            v.z = fmaxf(v.z, u.z); v.w = fmaxf(v.w, u.w); }
        }
      }
      float* xd = &Xs[tt * 33 + dc];
      xd[0] = v.x; xd[1] = v.y; xd[2] = v.z; xd[3] = v.w;
    }
    for (int j = tid; j < 1024; j += 256){
      int f = j >> 5, d = j & 31;
      Ws[d * 36 + f] = w[(size_t)f * D_ + d0 + d];
    }
    __syncthreads();
    const float* xr = &Xs[tok * 33];
    #pragma unroll 8
    for (int d = 0; d < 32; d++){
      float xv = xr[d];
      const float4* w4 = (const float4*)&Ws[d * 36 + grp * 4];
      float4 a = w4[0];
      acc[0] += xv * a.x; acc[1] += xv * a.y; acc[2] += xv * a.z; acc[3] += xv * a.w;
    }
    __syncthreads();
  }
  int g = G0 + tok;
  if (g < TOK_){
    float* op = (type == 0) ? (xb + (size_t)g * 32 + grp * 4)
                            : (cat + (size_t)g * 128 + 96 + grp * 4);
    #pragma unroll
    for (int j = 0; j < 4; j++) op[j] = acc[j];
  }
}

// fused K-convs: blockIdx.y selects {K39,K19,K9}. TC=32 tokens/block,
// 256 thr = 32 tok x 8 grp, 4 oc each. LDS tile + halo, padded pitch 33.
__global__ void k_convF(const float* __restrict__ xb, const float* __restrict__ wp39,
                        const float* __restrict__ wp19, const float* __restrict__ wp9,
                        float* __restrict__ cat){
  constexpr int TC = 32;
  __shared__ float Xs[(TC + 40) * 33];            // worst case 72 rows (incl zero row)
  int type = blockIdx.y;
  int KP   = type == 0 ? 40 : (type == 1 ? 20 : 12);
  int PAD  = type == 0 ? 19 : (type == 1 ? 9 : 4);
  int COFF = type << 5;
  const float* wp = type == 0 ? wp39 : (type == 1 ? wp19 : wp9);
  int RROWS = TC + KP - 1;                        // data rows; row RROWS = zeros
  int tid = threadIdx.x;
  int G0 = blockIdx.x * TC;
  for (int j = tid; j < (RROWS + 1) * 8; j += 256){
    int r = j >> 3, c = (j & 7) * 4;
    float4 v = {0.f, 0.f, 0.f, 0.f};
    if (r < RROWS){
      int g = G0 - PAD + r;
      if (g >= 0 && g < TOK_) v = *(const float4*)(xb + (size_t)g * 32 + c);
    }
    float* xd = &Xs[r * 33 + c];
    xd[0] = v.x; xd[1] = v.y; xd[2] = v.z; xd[3] = v.w;
  }
  __syncthreads();
  int tok = tid & 31, grp = tid >> 5;
  int g = G0 + tok;
  int t = g % T_;
  float acc[4] = {};
  const float* wb = wp + (size_t)(grp * 4) * 32 * KP;
  for (int q = 0; q < KP / 4; q++){
    int rs[4];
    #pragma unroll
    for (int j = 0; j < 4; j++){
      int k = q * 4 + j;
      unsigned tt = (unsigned)(t + k - PAD);
      rs[j] = (tt < (unsigned)T_) ? (tok + k) * 33 : RROWS * 33;
    }
    #pragma unroll 4
    for (int ic = 0; ic < 32; ic++){
      float x0 = Xs[rs[0] + ic], x1 = Xs[rs[1] + ic];
      float x2 = Xs[rs[2] + ic], x3 = Xs[rs[3] + ic];
      #pragma unroll
      for (int j = 0; j < 4; j++){
        float4 wv = *(const float4*)(wb + ((size_t)j * 32 + ic) * KP + q * 4);
        acc[j] += x0 * wv.x + x1 * wv.y + x2 * wv.z + x3 * wv.w;
      }
    }
  }
  if (g < TOK_){
    #pragma unroll
    for (int j = 0; j < 4; j++)
      cat[(size_t)g * 128 + COFF + grp * 4 + j] = acc[j];
  }
}

// repack conv weight (oc,ic,KW) -> (oc,ic,KP) zero-padded, KP%4==0
__global__ void k_repack(const float* __restrict__ w, float* __restrict__ wp,
                         int KW, int KP){
  int i = blockIdx.x * 256 + threadIdx.x;
  if (i >= 1024 * KP) return;
  int k = i % KP, oi = i / KP;
  wp[i] = (k < KW) ? w[(size_t)oi * KW + k] : 0.f;
}

// BN stats: coalesced grid-stride, per-channel atomics into stats[0..255]
__global__ void k_bnstat(const float* __restrict__ cat, float* __restrict__ stats){
  __shared__ float sm[512];
  int tid = threadIdx.x;
  float s = 0.f, q = 0.f;
  for (int rp = blockIdx.x; rp < TOK_ / 2; rp += gridDim.x){
    float v = cat[(size_t)rp * 256 + tid];
    s += v; q += v * v;
  }
  sm[tid] = s; sm[256 + tid] = q;
  __syncthreads();
  if (tid < 128){
    atomicAdd(&stats[tid], sm[tid] + sm[tid + 128]);
    atomicAdd(&stats[128 + tid], sm[256 + tid] + sm[256 + tid + 128]);
  }
}

// BN normalize + gelu, output bf16 for the MFMA projection GEMM
__global__ void k_bnact(const float* __restrict__ cat, __hip_bfloat16* __restrict__ catb,
                        const float* __restrict__ stats,
                        const float* __restrict__ g, const float* __restrict__ b){
  int i = blockIdx.x * 256 + threadIdx.x;
  int c = i & 127;
  float mu = stats[c] * (1.f / TOK_);
  float var = stats[128 + c] * (1.f / TOK_) - mu * mu;
  float v = cat[i];
  v = (v - mu) * rsqrtf(var + 1e-5f) * g[c] + b[c];
  catb[i] = __float2bfloat16(gelu_f(v));
}

__global__ void k_final(const float* __restrict__ xcat, const float* __restrict__ moe,
                        const float* __restrict__ iout, const float* __restrict__ pb,
                        float* __restrict__ out){
  size_t i = (size_t)blockIdx.x * 256 + threadIdx.x;
  int d = (int)(i & 511);
  out[i] = gelu_f(xcat[i] + moe[i] + iout[i] + pb[d]);
}

__global__ void k_loss(const float* __restrict__ gsum, float* __restrict__ o){
  if (threadIdx.x == 0){
    float l = 0;
    for (int e = 0; e < E_; e++){ float m = gsum[e] / (float)TOK_; l += m * m; }
    o[0] = (float)E_ * l;
  }
}

extern "C" void kernel_launch(void* const* d_in, const int* in_sizes, int n_in,
                              void* d_out, int out_size, void* d_ws, size_t ws_size,
                              hipStream_t stream){
  const float* x      = (const float*)d_in[0];
  const float* gamma1 = (const float*)d_in[2];
  const float* gamma2 = (const float*)d_in[3];
  const float* attn_w = (const float*)d_in[4];
  const float* attn_b = (const float*)d_in[5];
  const float* gate_w = (const float*)d_in[6];
  const float* ew1    = (const float*)d_in[7];
  const float* ew2    = (const float*)d_in[8];
  const float* bott_w = (const float*)d_in[9];
  const float* w39    = (const float*)d_in[10];
  const float* w19    = (const float*)d_in[11];
  const float* w9     = (const float*)d_in[12];
  const float* mp_w   = (const float*)d_in[13];
  const float* bn_g   = (const float*)d_in[14];
  const float* bn_b   = (const float*)d_in[15];
  const float* proj_w = (const float*)d_in[16];
  const float* proj_b = (const float*)d_in[17];
  float* out = (float*)d_out;

  float* ws = (float*)d_ws;
  size_t off = 0;
  auto alloc = [&](size_t n){ size_t o = off; off += (n + 63) & ~(size_t)63; return o; };
  size_t f_xs   = alloc(8392704);   // xs f32 / hbuf bf16 (TOK x 2048)
  size_t f_sc   = alloc(B_ * N_);
  size_t f_fl   = alloc(B_ * N_);
  size_t f_idx  = alloc(B_ * KL_);
  size_t f_xcat = alloc((size_t)TOK_ * D_);
  size_t f_xn2  = alloc((size_t)TOK_ * D_);
  size_t f_gate = alloc(TOK_ * E_);
  size_t f_gs   = alloc(64);
  size_t f_st   = alloc(256);
  size_t f_moe  = alloc((size_t)TOK_ * D_);
  size_t f_xb   = alloc((size_t)TOK_ * NF_);
  size_t f_cat  = alloc((size_t)TOK_ * 128);
  size_t f_iout = alloc((size_t)TOK_ * D_);        // hosts w1b,w2b,xn2b (bf16) early
  size_t f_part = alloc((size_t)64 * D_);
  size_t f_wp39 = alloc(1024 * 40);
  size_t f_wp19 = alloc(1024 * 20);
  size_t f_wp9  = alloc(1024 * 12);
  size_t f_pjb  = alloc(512 * 128 / 2 + 64);       // projb bf16 (512x128)
  size_t f_catb = alloc((size_t)TOK_ * 128 / 2 + 64); // catb bf16
  (void)ws_size; (void)in_sizes; (void)n_in; (void)out_size;

  float* xs   = ws + f_xs;
  float* sc   = ws + f_sc;
  int*   fl   = (int*)(ws + f_fl);
  int*   idx  = (int*)(ws + f_idx);
  float* xcat = ws + f_xcat;
  float* xn2  = ws + f_xn2;
  float* gate = ws + f_gate;
  float* gs   = ws + f_gs;
  float* stats= ws + f_st;
  float* moe  = ws + f_moe;
  float* xb   = ws + f_xb;
  float* cat  = ws + f_cat;
  float* iout = ws + f_iout;
  float* part = ws + f_part;
  float* wp39 = ws + f_wp39;
  float* wp19 = ws + f_wp19;
  float* wp9  = ws + f_wp9;
  __hip_bfloat16* projb = (__hip_bfloat16*)(ws + f_pjb);
  __hip_bfloat16* catb  = (__hip_bfloat16*)(ws + f_catb);
  __hip_bfloat16* hbuf = (__hip_bfloat16*)xs;              // TOK x 2048 bf16 (per group)
  __hip_bfloat16* w1b  = (__hip_bfloat16*)iout;            // [e][h][d]  4.2MB
  __hip_bfloat16* w2b  = w1b + (size_t)E_ * D_ * H_;       // grouped [g][d][2048]  4.2MB
  __hip_bfloat16* xn2b = w2b + (size_t)E_ * D_ * H_;       // TOK x D bf16  8.4MB

  hipMemsetAsync(gs, 0, (64 + 256) * sizeof(float), stream);   // gs + stats

  // weight preps
  k_trb<<<dim3(H_/32, D_/32, E_), 256, 0, stream>>>(ew1, w1b, D_, H_);   // -> [e][H][D]
  k_trb2<<<dim3(D_/32, H_/32, E_), 256, 0, stream>>>(ew2, w2b);          // -> [g][D][2048]
  k_trb<<<dim3(D_/32, 128/32, 1), 256, 0, stream>>>(proj_w, projb, 128, D_); // -> [512][128]
  k_repack<<<(1024 * 40 + 255) / 256, 256, 0, stream>>>(w39, wp39, 39, 40);
  k_repack<<<(1024 * 20 + 255) / 256, 256, 0, stream>>>(w19, wp19, 19, 20);
  k_repack<<<(1024 * 12 + 255) / 256, 256, 0, stream>>>(w9, wp9, 9, 12);

  k_rms_score<<<B_ * N_, 256, 0, stream>>>(x, gamma1, attn_w, attn_b, xs, sc);
  k_select<<<dim3(N_ / 256, B_), 256, 0, stream>>>(sc, fl);
  k_compact<<<B_, 64, 0, stream>>>(fl, idx);
  k_gather<<<(B_ * KL_ * D_) / 256, 256, 0, stream>>>(xs, idx, xcat);
  k_extra1<<<dim3(16, B_), 256, 0, stream>>>(xs, fl, part);
  k_extra2<<<dim3(2, B_), 256, 0, stream>>>(part, xcat);
  k_rms2gate<<<TOK_, 256, 0, stream>>>(xcat, gamma2, gate_w, xn2, xn2b, gate);
  k_gsum<<<32, 256, 0, stream>>>(gate, gs);

  int mt = (TOK_ + 127) / 128;   // 65
  // group 0: experts {0,1}; group 1: experts {2,3}
  gemm_bt<1><<<dim3(2048/128, mt), 256, 0, stream>>>(
      xn2b, w1b, nullptr, hbuf, TOK_, 2048, D_, gate);
  gemm_bt<0><<<dim3(D_/128, mt), 256, 0, stream>>>(
      hbuf, w2b, moe, nullptr, TOK_, D_, 2048, nullptr);
  gemm_bt<1><<<dim3(2048/128, mt), 256, 0, stream>>>(
      xn2b, w1b + (size_t)2 * H_ * D_, nullptr, hbuf, TOK_, 2048, D_, gate + 2);
  gemm_bt<2><<<dim3(D_/128, mt), 256, 0, stream>>>(
      hbuf, w2b + (size_t)D_ * 2048, moe, nullptr, TOK_, D_, 2048, nullptr);

  int t32 = (TOK_ + 31) / 32;  // 257
  k_1x1F<<<dim3(t32, 2), 256, 0, stream>>>(xn2, bott_w, mp_w, xb, cat);
  k_convF<<<dim3(t32, 3), 256, 0, stream>>>(xb, wp39, wp19, wp9, cat);
  k_bnstat<<<64, 256, 0, stream>>>(cat, stats);
  k_bnact<<<(TOK_ * 128) / 256, 256, 0, stream>>>(cat, catb, stats, bn_g, bn_b);
  gemm_bt<0><<<dim3(D_/128, mt), 256, 0, stream>>>(
      catb, projb, iout, nullptr, TOK_, D_, 128, nullptr);
  k_final<<<((size_t)TOK_ * D_) / 256, 256, 0, stream>>>(xcat, moe, iout, proj_b, out);
  k_loss<<<1, 64, 0, stream>>>(gs, out + (size_t)TOK_ * D_);
}

// Round 6
// 509.726 us; speedup vs baseline: 10.2688x; 1.2451x over previous
//
#include <hip/hip_runtime.h>
#include <hip/hip_bf16.h>
#include <math.h>

#define DEV __device__ __forceinline__

constexpr int B_ = 4, N_ = 4096, D_ = 512, E_ = 4, H_ = 1024, NF_ = 32;
constexpr int KL_ = 2048, T_ = KL_ + 1;          // 2049
constexpr int TOK_ = B_ * T_;                    // 8196
constexpr int SP_ = 2304;                        // padded rows per sample in xbp

typedef __bf16 bf16x8 __attribute__((ext_vector_type(8)));
typedef float f32x4 __attribute__((ext_vector_type(4)));

DEV float gelu_f(float x){ return 0.5f * x * (1.0f + erff(x * 0.7071067811865475f)); }

DEV float wave_sum(float v){
  #pragma unroll
  for (int off = 32; off > 0; off >>= 1) v += __shfl_down(v, off, 64);
  return v;
}

DEV float block_sum256(float v, float* sm){
  v = wave_sum(v);
  int lane = threadIdx.x & 63, wid = threadIdx.x >> 6;
  if (lane == 0) sm[wid] = v;
  __syncthreads();
  if (threadIdx.x == 0) sm[0] = sm[0] + sm[1] + sm[2] + sm[3];
  __syncthreads();
  float r = sm[0];
  __syncthreads();
  return r;
}

// rmsnorm1 + sigmoid score + xs = x_n * score.
__global__ void k_rms_score(const float* __restrict__ x, const float* __restrict__ g,
                            const float* __restrict__ aw, const float* __restrict__ ab,
                            float* __restrict__ xs, float* __restrict__ scores){
  __shared__ float sm[4];
  int row = blockIdx.x; int tid = threadIdx.x;
  const float* xr = x + (size_t)row * D_;
  float v0 = xr[tid], v1 = xr[tid + 256];
  float ss = block_sum256(v0 * v0 + v1 * v1, sm);
  float n = fmaxf(sqrtf(ss), 1e-12f);
  float inv = 22.627416997969522f / n;   // sqrt(512)
  float xn0 = v0 * inv * g[tid], xn1 = v1 * inv * g[tid + 256];
  float z = block_sum256(xn0 * aw[tid] + xn1 * aw[tid + 256], sm) + ab[0];
  float s = 1.0f / (1.0f + expf(-z));
  float* o = xs + (size_t)row * D_;
  o[tid] = xn0 * s; o[tid + 256] = xn1 * s;
  if (tid == 0) scores[row] = s;
}

// top-k selection flags via exact rank (ties -> lower index, matches lax.top_k)
__global__ void k_select(const float* __restrict__ scores, int* __restrict__ flags){
  __shared__ float s[N_];
  int b = blockIdx.y; int tid = threadIdx.x;
  int i = blockIdx.x * 256 + tid;
  const float4* src = (const float4*)(scores + (size_t)b * N_);
  for (int j = tid; j < N_ / 4; j += 256) ((float4*)s)[j] = src[j];
  __syncthreads();
  float si = s[i];
  int cnt = 0;
  for (int j = 0; j < N_; j += 4){
    float4 v = *(const float4*)&s[j];
    cnt += (v.x > si) || (v.x == si && (j + 0) < i);
    cnt += (v.y > si) || (v.y == si && (j + 1) < i);
    cnt += (v.z > si) || (v.z == si && (j + 2) < i);
    cnt += (v.w > si) || (v.w == si && (j + 3) < i);
  }
  flags[(size_t)b * N_ + i] = (cnt < KL_) ? 1 : 0;
}

__global__ void k_compact(const int* __restrict__ flags, int* __restrict__ idx){
  int b = blockIdx.x; int lane = threadIdx.x;
  int base = 0;
  for (int chunk = 0; chunk < N_ / 64; chunk++){
    int t = chunk * 64 + lane;
    int fl = flags[(size_t)b * N_ + t];
    unsigned long long m = __ballot(fl != 0);
    int pre = __popcll(m & ((1ull << lane) - 1ull));
    if (fl) idx[(size_t)b * KL_ + base + pre] = t;
    base += __popcll(m);
  }
}

__global__ void k_gather(const float* __restrict__ xs, const int* __restrict__ idx,
                         float* __restrict__ xcat){
  size_t i = (size_t)blockIdx.x * 256 + threadIdx.x;
  int d = (int)(i & 511);
  int p = (int)((i >> 9) & (KL_ - 1));
  int b = (int)(i >> 20);
  int tok = idx[(size_t)b * KL_ + p];
  xcat[((size_t)b * T_ + p) * D_ + d] = xs[((size_t)b * N_ + tok) * D_ + d];
}

// extra row = sum of unselected xs rows: coalesced two-stage reduction
__global__ void k_extra1(const float* __restrict__ xs, const int* __restrict__ flags,
                         float* __restrict__ part){
  int b = blockIdx.y, blk = blockIdx.x;
  int tid = threadIdx.x;
  const int* fb = flags + (size_t)b * N_ + blk * 256;
  const float2* xp = (const float2*)(xs + ((size_t)b * N_ + blk * 256) * D_) + tid;
  float2 acc = {0.f, 0.f};
  for (int i = 0; i < 256; i++){
    if (!fb[i]){
      float2 v = xp[(size_t)i * 256];
      acc.x += v.x; acc.y += v.y;
    }
  }
  float* pr = part + ((size_t)(b * 16 + blk)) * D_;
  pr[tid * 2] = acc.x; pr[tid * 2 + 1] = acc.y;
}

__global__ void k_extra2(const float* __restrict__ part, float* __restrict__ xcat){
  int b = blockIdx.y; int d = blockIdx.x * 256 + threadIdx.x;
  float s = 0.f;
  for (int i = 0; i < 16; i++) s += part[((size_t)(b * 16 + i)) * D_ + d];
  xcat[((size_t)b * T_ + KL_) * D_ + d] = s;
}

// rmsnorm2 + fused gate logits/softmax. Writes xn2 (f32), xn2b (bf16), gate.
__global__ void k_rms2gate(const float* __restrict__ xc, const float* __restrict__ g,
                           const float* __restrict__ gw,
                           float* __restrict__ xn2, __hip_bfloat16* __restrict__ xn2b,
                           float* __restrict__ gate){
  __shared__ float sm[4];
  __shared__ float sg[16];
  int row = blockIdx.x; int tid = threadIdx.x;
  const float* xr = xc + (size_t)row * D_;
  float v0 = xr[tid], v1 = xr[tid + 256];
  float ss = block_sum256(v0 * v0 + v1 * v1, sm);
  float n = fmaxf(sqrtf(ss), 1e-12f);
  float inv = 22.627416997969522f / n;
  float xn0 = v0 * inv * g[tid], xn1 = v1 * inv * g[tid + 256];
  float* o = xn2 + (size_t)row * D_;
  o[tid] = xn0; o[tid + 256] = xn1;
  __hip_bfloat16* ob = xn2b + (size_t)row * D_;
  ob[tid] = __float2bfloat16(xn0); ob[tid + 256] = __float2bfloat16(xn1);
  const float4* gw4 = (const float4*)gw;
  float4 wa = gw4[tid], wb = gw4[tid + 256];
  float l0 = xn0 * wa.x + xn1 * wb.x, l1 = xn0 * wa.y + xn1 * wb.y;
  float l2 = xn0 * wa.z + xn1 * wb.z, l3 = xn0 * wa.w + xn1 * wb.w;
  l0 = wave_sum(l0); l1 = wave_sum(l1); l2 = wave_sum(l2); l3 = wave_sum(l3);
  int lane = tid & 63, wid = tid >> 6;
  if (lane == 0){ sg[wid*4+0]=l0; sg[wid*4+1]=l1; sg[wid*4+2]=l2; sg[wid*4+3]=l3; }
  __syncthreads();
  if (tid == 0){
    float a0 = sg[0]+sg[4]+sg[8]+sg[12];
    float a1 = sg[1]+sg[5]+sg[9]+sg[13];
    float a2 = sg[2]+sg[6]+sg[10]+sg[14];
    float a3 = sg[3]+sg[7]+sg[11]+sg[15];
    float m = fmaxf(fmaxf(a0, a1), fmaxf(a2, a3));
    float e0 = expf(a0-m), e1 = expf(a1-m), e2 = expf(a2-m), e3 = expf(a3-m);
    float is = 1.f / (e0+e1+e2+e3);
    float* gr = gate + (size_t)row * 4;
    gr[0]=e0*is; gr[1]=e1*is; gr[2]=e2*is; gr[3]=e3*is;
  }
}

// reduce gate(TOK,4) -> gs[4]. 32 blocks, 128 spread atomics total.
__global__ void k_gsum(const float* __restrict__ gate, float* __restrict__ gs){
  __shared__ float sm[16];
  int tid = threadIdx.x;
  float4 a = {0.f, 0.f, 0.f, 0.f};
  for (int r = blockIdx.x * 256 + tid; r < TOK_; r += gridDim.x * 256){
    float4 v = *(const float4*)(gate + (size_t)r * 4);
    a.x += v.x; a.y += v.y; a.z += v.z; a.w += v.w;
  }
  a.x = wave_sum(a.x); a.y = wave_sum(a.y); a.z = wave_sum(a.z); a.w = wave_sum(a.w);
  int lane = tid & 63, wid = tid >> 6;
  if (lane == 0){ sm[wid*4]=a.x; sm[wid*4+1]=a.y; sm[wid*4+2]=a.z; sm[wid*4+3]=a.w; }
  __syncthreads();
  if (tid < 4){
    float s = sm[tid] + sm[4+tid] + sm[8+tid] + sm[12+tid];
    atomicAdd(&gs[tid], s);
  }
}

// LDS-tiled transpose+convert: in (R x C) f32 -> out (C x R) bf16, batched over z.
__global__ void k_trb(const float* __restrict__ in, __hip_bfloat16* __restrict__ out,
                      int R, int C){
  __shared__ float t[32][33];
  int mat = blockIdx.z;
  in  += (size_t)mat * R * C;
  out += (size_t)mat * R * C;
  int c0 = blockIdx.x * 32, r0 = blockIdx.y * 32;
  int j = threadIdx.x & 31, i4 = threadIdx.x >> 5;
  #pragma unroll
  for (int k = 0; k < 4; k++){
    int i = i4 * 4 + k;
    t[i][j] = in[(size_t)(r0 + i) * C + c0 + j];
  }
  __syncthreads();
  #pragma unroll
  for (int k = 0; k < 4; k++){
    int i = i4 * 4 + k;
    out[(size_t)(c0 + i) * R + r0 + j] = __float2bfloat16(t[j][i]);
  }
}

// ew2 (E,H,D) -> w2b grouped: w2b[(e>>1)*D*2048 + d*2048 + (e&1)*H + h]
__global__ void k_trb2(const float* __restrict__ in, __hip_bfloat16* __restrict__ out){
  __shared__ float t[32][33];
  int e = blockIdx.z;
  const float* ip = in + (size_t)e * H_ * D_;
  __hip_bfloat16* op = out + (size_t)(e >> 1) * D_ * 2048 + (e & 1) * H_;
  int c0 = blockIdx.x * 32, r0 = blockIdx.y * 32;   // c over D, r over H
  int j = threadIdx.x & 31, i4 = threadIdx.x >> 5;
  #pragma unroll
  for (int k = 0; k < 4; k++){
    int i = i4 * 4 + k;
    t[i][j] = ip[(size_t)(r0 + i) * D_ + c0 + j];
  }
  __syncthreads();
  #pragma unroll
  for (int k = 0; k < 4; k++){
    int i = i4 * 4 + k;
    op[(size_t)(c0 + i) * 2048 + r0 + j] = __float2bfloat16(t[j][i]);
  }
}

// pack conv weights (oc,ic,KW) f32 -> wcb bf16 [type][oc][k*32+ic], K zero-padded
__global__ void k_wpack(const float* __restrict__ w39, const float* __restrict__ w19,
                        const float* __restrict__ w9, __hip_bfloat16* __restrict__ wcb){
  int i = blockIdx.x * 256 + threadIdx.x;
  if (i >= 73728) return;
  const float* w; int KP, KW, base;
  if (i < 40960){ w = w39; KP = 40; KW = 39; base = 0; }
  else if (i < 61440){ w = w19; KP = 20; KW = 19; base = 40960; }
  else { w = w9; KP = 12; KW = 9; base = 61440; }
  int li = i - base;
  int oc = li / (32 * KP);
  int rem = li % (32 * KP);
  int k = rem >> 5, ic = rem & 31;
  float v = (k < KW) ? w[((size_t)oc * 32 + ic) * KW + k] : 0.f;
  wcb[i] = __float2bfloat16(v);
}

// bf16 MFMA GEMM, B pre-transposed (Bt: N x K row-major). C = A(MxK) @ B(KxN).
// 128x128 tile, BK=32, 4 waves. EPI 0: Cf = acc;
// EPI 1: Cb = bf16(gelu(acc) * gatep[row*4 + (col>>10)]); EPI 2: Cf += acc.
template<int EPI>
__launch_bounds__(256)
__global__ void gemm_bt(const __hip_bfloat16* __restrict__ A,
                        const __hip_bfloat16* __restrict__ Bt,
                        float* __restrict__ Cf, __hip_bfloat16* __restrict__ Cb,
                        int M, int N, int K, const float* __restrict__ gatep){
  __shared__ __align__(16) char smem[2][16384];   // [buf][A 8K | B 8K]
  int tid = threadIdx.x;
  int m0 = blockIdx.y * 128, n0 = blockIdx.x * 128;
  int ln = tid & 63, wid = tid >> 6;
  int wm = wid >> 1, wn = wid & 1;

  f32x4 acc[4][4] = {};

  auto stage = [&](int buf, int k0){
    #pragma unroll
    for (int c = 0; c < 2; c++){
      int ii = tid + c * 256;
      int r = ii >> 2, s = ii & 3;
      int gm = m0 + r; gm = gm < M ? gm : M - 1;
      const __hip_bfloat16* gp = A + (size_t)gm * K + (k0 + ((s ^ (r & 3)) << 3));
      __builtin_amdgcn_global_load_lds(
          (const __attribute__((address_space(1))) void*)gp,
          (__attribute__((address_space(3))) void*)&smem[buf][ii * 16], 16, 0, 0);
    }
    #pragma unroll
    for (int c = 0; c < 2; c++){
      int ii = tid + c * 256;
      int r = ii >> 2, s = ii & 3;
      const __hip_bfloat16* gp = Bt + (size_t)(n0 + r) * K + (k0 + ((s ^ (r & 3)) << 3));
      __builtin_amdgcn_global_load_lds(
          (const __attribute__((address_space(1))) void*)gp,
          (__attribute__((address_space(3))) void*)&smem[buf][8192 + ii * 16], 16, 0, 0);
    }
  };

  int nk = K >> 5;
  stage(0, 0);
  __syncthreads();
  int slotb = (((ln >> 4) ^ (ln & 3)) << 4);   // swizzled 16B slot for my kgrp
  for (int t = 0; t < nk; t++){
    int buf = t & 1;
    if (t + 1 < nk) stage(buf ^ 1, (t + 1) << 5);
    bf16x8 af[4], bfr[4];
    #pragma unroll
    for (int m = 0; m < 4; m++){
      int R = wm * 64 + m * 16 + (ln & 15);
      af[m] = *(const bf16x8*)&smem[buf][R * 64 + slotb];
    }
    #pragma unroll
    for (int n = 0; n < 4; n++){
      int R = wn * 64 + n * 16 + (ln & 15);
      bfr[n] = *(const bf16x8*)&smem[buf][8192 + R * 64 + slotb];
    }
    #pragma unroll
    for (int m = 0; m < 4; m++)
      #pragma unroll
      for (int n = 0; n < 4; n++)
        acc[m][n] = __builtin_amdgcn_mfma_f32_16x16x32_bf16(af[m], bfr[n], acc[m][n], 0, 0, 0);
    __syncthreads();
  }

  #pragma unroll
  for (int m = 0; m < 4; m++){
    int rb = m0 + wm * 64 + m * 16 + ((ln >> 4) << 2);
    #pragma unroll
    for (int n = 0; n < 4; n++){
      int col = n0 + wn * 64 + n * 16 + (ln & 15);
      #pragma unroll
      for (int r = 0; r < 4; r++){
        int row = rb + r;
        if (row < M){
          size_t ci = (size_t)row * N + col;
          float v = acc[m][n][r];
          if (EPI == 0) Cf[ci] = v;
          else if (EPI == 1)
            Cb[ci] = __float2bfloat16(gelu_f(v) * gatep[(size_t)row * 4 + (col >> 10)]);
          else Cf[ci] += v;
        }
      }
    }
  }
}

// fused 1x1 convs: y=0 -> bott_w -> xbp (bf16, padded layout); y=1 -> mp_w -> cat.
__global__ void k_1x1F(const float* __restrict__ xn2, const float* __restrict__ bw,
                       const float* __restrict__ mw,
                       __hip_bfloat16* __restrict__ xbp, float* __restrict__ cat){
  __shared__ float Xs[32 * 33];
  __shared__ float Ws[32 * 36];
  int type = blockIdx.y;
  const float* w = type == 0 ? bw : mw;
  int tid = threadIdx.x;
  int G0 = blockIdx.x * 32;
  int tok = tid & 31, grp = tid >> 5;
  float acc[4] = {};
  for (int d0 = 0; d0 < D_; d0 += 32){
    {
      int tt = tid >> 3, dc = (tid & 7) * 4;
      int g = G0 + tt;
      float4 v = {0.f, 0.f, 0.f, 0.f};
      if (g < TOK_){
        const float* p = xn2 + (size_t)g * D_ + d0 + dc;
        v = *(const float4*)p;
        if (type == 1){
          int t = g % T_;
          if (t > 0){ float4 u = *(const float4*)(p - D_);
            v.x = fmaxf(v.x, u.x); v.y = fmaxf(v.y, u.y);
            v.z = fmaxf(v.z, u.z); v.w = fmaxf(v.w, u.w); }
          if (t < T_ - 1){ float4 u = *(const float4*)(p + D_);
            v.x = fmaxf(v.x, u.x); v.y = fmaxf(v.y, u.y);
            v.z = fmaxf(v.z, u.z); v.w = fmaxf(v.w, u.w); }
        }
      }
      float* xd = &Xs[tt * 33 + dc];
      xd[0] = v.x; xd[1] = v.y; xd[2] = v.z; xd[3] = v.w;
    }
    for (int j = tid; j < 1024; j += 256){
      int f = j >> 5, d = j & 31;
      Ws[d * 36 + f] = w[(size_t)f * D_ + d0 + d];
    }
    __syncthreads();
    const float* xr = &Xs[tok * 33];
    #pragma unroll 8
    for (int d = 0; d < 32; d++){
      float xv = xr[d];
      const float4* w4 = (const float4*)&Ws[d * 36 + grp * 4];
      float4 a = w4[0];
      acc[0] += xv * a.x; acc[1] += xv * a.y; acc[2] += xv * a.z; acc[3] += xv * a.w;
    }
    __syncthreads();
  }
  int g = G0 + tok;
  if (g < TOK_){
    if (type == 0){
      int bb = g / T_, t = g % T_;
      __hip_bfloat16* op = xbp + ((size_t)(bb * SP_ + 32 + t)) * 32 + grp * 4;
      #pragma unroll
      for (int j = 0; j < 4; j++) op[j] = __float2bfloat16(acc[j]);
    } else {
      float* op = cat + (size_t)g * 128 + 96 + grp * 4;
      #pragma unroll
      for (int j = 0; j < 4; j++) op[j] = acc[j];
    }
  }
}

// MFMA implicit-GEMM conv. Block: 128 tokens x 32 oc, 4 waves (each 32 tok x 32 oc).
// A[t][r=k*32+ic] = xbp[sample][t+k-PAD][ic]  (staged halo tile, staged ONCE)
// B[oc][r] = wcb[type][oc][r]                 (registers, direct from L2, 1-step prefetch)
template<int KP, int PAD, int OFF, int TYPE>
DEV void convm_body(const __hip_bfloat16* __restrict__ xbp,
                    const __hip_bfloat16* __restrict__ wcb,
                    float* __restrict__ cat, char* smem){
  constexpr int R = KP * 32;
  int t0 = blockIdx.x * 128, b = blockIdx.y;
  int tid = threadIdx.x;
  // stage 192 halo rows (linear LDS dest, inverse-swizzled global source)
  for (int j = tid; j < 768; j += 256){
    int r = j >> 2, c = j & 3;
    int rg = b * SP_ + 32 + t0 - PAD + r;
    const __hip_bfloat16* gp = xbp + (size_t)rg * 32 + ((c ^ (r & 3)) << 3);
    __builtin_amdgcn_global_load_lds(
        (const __attribute__((address_space(1))) void*)gp,
        (__attribute__((address_space(3))) void*)(smem + j * 16), 16, 0, 0);
  }
  __syncthreads();
  int ln = tid & 63, wid = tid >> 6;
  int lr = ln & 15, lg = ln >> 4;
  int tb = wid * 32;
  const __hip_bfloat16* wt = wcb + OFF;
  const __hip_bfloat16* bp0 = wt + (size_t)lr * R + lg * 8;
  const __hip_bfloat16* bp1 = wt + (size_t)(16 + lr) * R + lg * 8;
  f32x4 acc[2][2] = {};
  bf16x8 bc0 = *(const bf16x8*)bp0;
  bf16x8 bc1 = *(const bf16x8*)bp1;
  #pragma unroll 4
  for (int s = 0; s < KP; s++){
    bf16x8 bn0 = bc0, bn1 = bc1;
    if (s + 1 < KP){
      bn0 = *(const bf16x8*)(bp0 + (s + 1) * 32);
      bn1 = *(const bf16x8*)(bp1 + (s + 1) * 32);
    }
    int ra0 = tb + lr + s;
    int ra1 = tb + 16 + lr + s;
    bf16x8 a0 = *(const bf16x8*)(smem + ra0 * 64 + ((lg ^ (ra0 & 3)) << 4));
    bf16x8 a1 = *(const bf16x8*)(smem + ra1 * 64 + ((lg ^ (ra1 & 3)) << 4));
    acc[0][0] = __builtin_amdgcn_mfma_f32_16x16x32_bf16(a0, bc0, acc[0][0], 0, 0, 0);
    acc[0][1] = __builtin_amdgcn_mfma_f32_16x16x32_bf16(a0, bc1, acc[0][1], 0, 0, 0);
    acc[1][0] = __builtin_amdgcn_mfma_f32_16x16x32_bf16(a1, bc0, acc[1][0], 0, 0, 0);
    acc[1][1] = __builtin_amdgcn_mfma_f32_16x16x32_bf16(a1, bc1, acc[1][1], 0, 0, 0);
    bc0 = bn0; bc1 = bn1;
  }
  #pragma unroll
  for (int m = 0; m < 2; m++){
    int rb = tb + m * 16 + ((ln >> 4) << 2);
    #pragma unroll
    for (int n = 0; n < 2; n++){
      int oc = n * 16 + lr;
      #pragma unroll
      for (int j2 = 0; j2 < 4; j2++){
        int tp = t0 + rb + j2;
        if (tp < T_)
          cat[((size_t)b * T_ + tp) * 128 + TYPE * 32 + oc] = acc[m][n][j2];
      }
    }
  }
}

__global__ __launch_bounds__(256)
void k_convM(const __hip_bfloat16* __restrict__ xbp,
             const __hip_bfloat16* __restrict__ wcb, float* __restrict__ cat){
  __shared__ __align__(16) char smem[192 * 64];
  if (blockIdx.z == 0)      convm_body<40, 19, 0,     0>(xbp, wcb, cat, smem);
  else if (blockIdx.z == 1) convm_body<20, 9,  40960, 1>(xbp, wcb, cat, smem);
  else                      convm_body<12, 4,  61440, 2>(xbp, wcb, cat, smem);
}

// BN stats: coalesced grid-stride, per-channel atomics into stats[0..255]
__global__ void k_bnstat(const float* __restrict__ cat, float* __restrict__ stats){
  __shared__ float sm[512];
  int tid = threadIdx.x;
  float s = 0.f, q = 0.f;
  for (int rp = blockIdx.x; rp < TOK_ / 2; rp += gridDim.x){
    float v = cat[(size_t)rp * 256 + tid];
    s += v; q += v * v;
  }
  sm[tid] = s; sm[256 + tid] = q;
  __syncthreads();
  if (tid < 128){
    atomicAdd(&stats[tid], sm[tid] + sm[tid + 128]);
    atomicAdd(&stats[128 + tid], sm[256 + tid] + sm[256 + tid + 128]);
  }
}

// BN normalize + gelu, output bf16 for the MFMA projection GEMM
__global__ void k_bnact(const float* __restrict__ cat, __hip_bfloat16* __restrict__ catb,
                        const float* __restrict__ stats,
                        const float* __restrict__ g, const float* __restrict__ b){
  int i = blockIdx.x * 256 + threadIdx.x;
  int c = i & 127;
  float mu = stats[c] * (1.f / TOK_);
  float var = stats[128 + c] * (1.f / TOK_) - mu * mu;
  float v = cat[i];
  v = (v - mu) * rsqrtf(var + 1e-5f) * g[c] + b[c];
  catb[i] = __float2bfloat16(gelu_f(v));
}

__global__ void k_final(const float* __restrict__ xcat, const float* __restrict__ moe,
                        const float* __restrict__ iout, const float* __restrict__ pb,
                        float* __restrict__ out){
  size_t i = (size_t)blockIdx.x * 256 + threadIdx.x;
  int d = (int)(i & 511);
  out[i] = gelu_f(xcat[i] + moe[i] + iout[i] + pb[d]);
}

__global__ void k_loss(const float* __restrict__ gsum, float* __restrict__ o){
  if (threadIdx.x == 0){
    float l = 0;
    for (int e = 0; e < E_; e++){ float m = gsum[e] / (float)TOK_; l += m * m; }
    o[0] = (float)E_ * l;
  }
}

extern "C" void kernel_launch(void* const* d_in, const int* in_sizes, int n_in,
                              void* d_out, int out_size, void* d_ws, size_t ws_size,
                              hipStream_t stream){
  const float* x      = (const float*)d_in[0];
  const float* gamma1 = (const float*)d_in[2];
  const float* gamma2 = (const float*)d_in[3];
  const float* attn_w = (const float*)d_in[4];
  const float* attn_b = (const float*)d_in[5];
  const float* gate_w = (const float*)d_in[6];
  const float* ew1    = (const float*)d_in[7];
  const float* ew2    = (const float*)d_in[8];
  const float* bott_w = (const float*)d_in[9];
  const float* w39    = (const float*)d_in[10];
  const float* w19    = (const float*)d_in[11];
  const float* w9     = (const float*)d_in[12];
  const float* mp_w   = (const float*)d_in[13];
  const float* bn_g   = (const float*)d_in[14];
  const float* bn_b   = (const float*)d_in[15];
  const float* proj_w = (const float*)d_in[16];
  const float* proj_b = (const float*)d_in[17];
  float* out = (float*)d_out;

  float* ws = (float*)d_ws;
  size_t off = 0;
  auto alloc = [&](size_t n){ size_t o = off; off += (n + 63) & ~(size_t)63; return o; };
  size_t f_xs   = alloc(8392704);   // xs f32 / hbuf bf16 (TOK x 2048)
  size_t f_sc   = alloc(B_ * N_);
  size_t f_fl   = alloc(B_ * N_);
  size_t f_idx  = alloc(B_ * KL_);
  size_t f_xcat = alloc((size_t)TOK_ * D_);
  size_t f_xn2  = alloc((size_t)TOK_ * D_);
  size_t f_gate = alloc(TOK_ * E_);
  size_t f_gs   = alloc(64);
  size_t f_st   = alloc(256);
  size_t f_moe  = alloc((size_t)TOK_ * D_);
  size_t f_xbp  = alloc((size_t)B_ * SP_ * 32 / 2);   // bf16 padded conv input
  size_t f_cat  = alloc((size_t)TOK_ * 128);
  size_t f_iout = alloc((size_t)TOK_ * D_);        // hosts w1b,w2b,xn2b (bf16) early
  size_t f_part = alloc((size_t)64 * D_);
  size_t f_wcb  = alloc(73728 / 2 + 64);           // packed conv weights bf16
  size_t f_pjb  = alloc(512 * 128 / 2 + 64);       // projb bf16 (512x128)
  size_t f_catb = alloc((size_t)TOK_ * 128 / 2 + 64); // catb bf16
  (void)ws_size; (void)in_sizes; (void)n_in; (void)out_size;

  float* xs   = ws + f_xs;
  float* sc   = ws + f_sc;
  int*   fl   = (int*)(ws + f_fl);
  int*   idx  = (int*)(ws + f_idx);
  float* xcat = ws + f_xcat;
  float* xn2  = ws + f_xn2;
  float* gate = ws + f_gate;
  float* gs   = ws + f_gs;
  float* stats= ws + f_st;
  float* moe  = ws + f_moe;
  float* cat  = ws + f_cat;
  float* iout = ws + f_iout;
  float* part = ws + f_part;
  __hip_bfloat16* xbp   = (__hip_bfloat16*)(ws + f_xbp);
  __hip_bfloat16* wcb   = (__hip_bfloat16*)(ws + f_wcb);
  __hip_bfloat16* projb = (__hip_bfloat16*)(ws + f_pjb);
  __hip_bfloat16* catb  = (__hip_bfloat16*)(ws + f_catb);
  __hip_bfloat16* hbuf = (__hip_bfloat16*)xs;              // TOK x 2048 bf16 (per group)
  __hip_bfloat16* w1b  = (__hip_bfloat16*)iout;            // [e][h][d]  4.2MB
  __hip_bfloat16* w2b  = w1b + (size_t)E_ * D_ * H_;       // grouped [g][d][2048]  4.2MB
  __hip_bfloat16* xn2b = w2b + (size_t)E_ * D_ * H_;       // TOK x D bf16  8.4MB

  hipMemsetAsync(gs, 0, (64 + 256) * sizeof(float), stream);   // gs + stats
  hipMemsetAsync(xbp, 0, (size_t)B_ * SP_ * 32 * sizeof(__hip_bfloat16), stream);

  // weight preps
  k_trb<<<dim3(H_/32, D_/32, E_), 256, 0, stream>>>(ew1, w1b, D_, H_);   // -> [e][H][D]
  k_trb2<<<dim3(D_/32, H_/32, E_), 256, 0, stream>>>(ew2, w2b);          // -> [g][D][2048]
  k_trb<<<dim3(D_/32, 128/32, 1), 256, 0, stream>>>(proj_w, projb, 128, D_); // -> [512][128]
  k_wpack<<<288, 256, 0, stream>>>(w39, w19, w9, wcb);

  k_rms_score<<<B_ * N_, 256, 0, stream>>>(x, gamma1, attn_w, attn_b, xs, sc);
  k_select<<<dim3(N_ / 256, B_), 256, 0, stream>>>(sc, fl);
  k_compact<<<B_, 64, 0, stream>>>(fl, idx);
  k_gather<<<(B_ * KL_ * D_) / 256, 256, 0, stream>>>(xs, idx, xcat);
  k_extra1<<<dim3(16, B_), 256, 0, stream>>>(xs, fl, part);
  k_extra2<<<dim3(2, B_), 256, 0, stream>>>(part, xcat);
  k_rms2gate<<<TOK_, 256, 0, stream>>>(xcat, gamma2, gate_w, xn2, xn2b, gate);
  k_gsum<<<32, 256, 0, stream>>>(gate, gs);

  int mt = (TOK_ + 127) / 128;   // 65
  // group 0: experts {0,1}; group 1: experts {2,3}
  gemm_bt<1><<<dim3(2048/128, mt), 256, 0, stream>>>(
      xn2b, w1b, nullptr, hbuf, TOK_, 2048, D_, gate);
  gemm_bt<0><<<dim3(D_/128, mt), 256, 0, stream>>>(
      hbuf, w2b, moe, nullptr, TOK_, D_, 2048, nullptr);
  gemm_bt<1><<<dim3(2048/128, mt), 256, 0, stream>>>(
      xn2b, w1b + (size_t)2 * H_ * D_, nullptr, hbuf, TOK_, 2048, D_, gate + 2);
  gemm_bt<2><<<dim3(D_/128, mt), 256, 0, stream>>>(
      hbuf, w2b + (size_t)D_ * 2048, moe, nullptr, TOK_, D_, 2048, nullptr);

  int t32 = (TOK_ + 31) / 32;  // 257
  k_1x1F<<<dim3(t32, 2), 256, 0, stream>>>(xn2, bott_w, mp_w, xbp, cat);
  k_convM<<<dim3(17, 4, 3), 256, 0, stream>>>(xbp, wcb, cat);
  k_bnstat<<<64, 256, 0, stream>>>(cat, stats);
  k_bnact<<<(TOK_ * 128) / 256, 256, 0, stream>>>(cat, catb, stats, bn_g, bn_b);
  gemm_bt<0><<<dim3(D_/128, mt), 256, 0, stream>>>(
      catb, projb, iout, nullptr, TOK_, D_, 128, nullptr);
  k_final<<<((size_t)TOK_ * D_) / 256, 256, 0, stream>>>(xcat, moe, iout, proj_b, out);
  k_loss<<<1, 64, 0, stream>>>(gs, out + (size_t)TOK_ * D_);
}

// Round 7
// 418.068 us; speedup vs baseline: 12.5201x; 1.2192x over previous
//
#include <hip/hip_runtime.h>
#include <hip/hip_bf16.h>
#include <math.h>

#define DEV __device__ __forceinline__

constexpr int B_ = 4, N_ = 4096, D_ = 512, E_ = 4, H_ = 1024, NF_ = 32;
constexpr int KL_ = 2048, T_ = KL_ + 1;          // 2049
constexpr int TOK_ = B_ * T_;                    // 8196
constexpr int SP_ = 2304;                        // padded rows per sample in xbp

typedef __bf16 bf16x8 __attribute__((ext_vector_type(8)));
typedef float f32x4 __attribute__((ext_vector_type(4)));

DEV float gelu_f(float x){ return 0.5f * x * (1.0f + erff(x * 0.7071067811865475f)); }

DEV float wave_sum(float v){
  #pragma unroll
  for (int off = 32; off > 0; off >>= 1) v += __shfl_down(v, off, 64);
  return v;
}

DEV float block_sum256(float v, float* sm){
  v = wave_sum(v);
  int lane = threadIdx.x & 63, wid = threadIdx.x >> 6;
  if (lane == 0) sm[wid] = v;
  __syncthreads();
  if (threadIdx.x == 0) sm[0] = sm[0] + sm[1] + sm[2] + sm[3];
  __syncthreads();
  float r = sm[0];
  __syncthreads();
  return r;
}

// rmsnorm1 + sigmoid score. Writes ONLY per-row scalars:
// scores[row] = sigmoid(z), scale[row] = (sqrt(512)/||x||) * score.
// (xs = x * scale * gamma1 is reconstructed on the fly downstream.)
__global__ void k_rms_score(const float* __restrict__ x, const float* __restrict__ g,
                            const float* __restrict__ aw, const float* __restrict__ ab,
                            float* __restrict__ scores, float* __restrict__ scale){
  __shared__ float sm[4];
  int row = blockIdx.x; int tid = threadIdx.x;
  const float* xr = x + (size_t)row * D_;
  float v0 = xr[tid], v1 = xr[tid + 256];
  float ss = block_sum256(v0 * v0 + v1 * v1, sm);
  float a  = block_sum256(v0 * g[tid] * aw[tid] + v1 * g[tid + 256] * aw[tid + 256], sm);
  float n = fmaxf(sqrtf(ss), 1e-12f);
  float inv = 22.627416997969522f / n;   // sqrt(512)
  float z = inv * a + ab[0];
  float s = 1.0f / (1.0f + expf(-z));
  if (tid == 0){ scores[row] = s; scale[row] = inv * s; }
}

// top-k selection flags via exact rank (ties -> lower index, matches lax.top_k).
// 64 tokens/block x 4 count-parts; 256 blocks total -> latency hidden.
__global__ void k_select(const float* __restrict__ scores, int* __restrict__ flags){
  __shared__ float s[N_];
  __shared__ int cnts[4][64];
  int b = blockIdx.y; int tid = threadIdx.x;
  int tile = blockIdx.x * 64;
  const float4* src = (const float4*)(scores + (size_t)b * N_);
  for (int j = tid; j < N_ / 4; j += 256) ((float4*)s)[j] = src[j];
  __syncthreads();
  int tok = tid & 63, part = tid >> 6;
  int i = tile + tok;
  float si = s[i];
  int cnt = 0;
  const float4* sp = (const float4*)(s + part * 1024);
  int jb = part * 1024;
  #pragma unroll 4
  for (int j = 0; j < 256; j++){
    float4 v = sp[j];
    int j4 = jb + j * 4;
    cnt += (v.x > si) || (v.x == si && (j4 + 0) < i);
    cnt += (v.y > si) || (v.y == si && (j4 + 1) < i);
    cnt += (v.z > si) || (v.z == si && (j4 + 2) < i);
    cnt += (v.w > si) || (v.w == si && (j4 + 3) < i);
  }
  cnts[part][tok] = cnt;
  __syncthreads();
  if (tid < 64){
    int c = cnts[0][tid] + cnts[1][tid] + cnts[2][tid] + cnts[3][tid];
    flags[(size_t)b * N_ + tile + tid] = (c < KL_) ? 1 : 0;
  }
}

// compact selected indices ascending. One 256-thread block per batch:
// per-thread 16-flag count -> wave shfl scan -> scatter.
__global__ void k_compact(const int* __restrict__ flags, int* __restrict__ idx){
  __shared__ int wsum[4];
  int b = blockIdx.x; int tid = threadIdx.x;
  const int* fb = flags + (size_t)b * N_;
  int f[16]; int cnt = 0;
  #pragma unroll
  for (int i = 0; i < 16; i++){ f[i] = fb[tid * 16 + i]; cnt += f[i]; }
  int lane = tid & 63, wid = tid >> 6;
  int v = cnt;
  #pragma unroll
  for (int off = 1; off < 64; off <<= 1){
    int t = __shfl_up(v, off, 64);
    if (lane >= off) v += t;
  }
  if (lane == 63) wsum[wid] = v;
  __syncthreads();
  int base = v - cnt;   // exclusive within wave
  for (int w = 0; w < wid; w++) base += wsum[w];
  int* ib = idx + (size_t)b * KL_;
  #pragma unroll
  for (int i = 0; i < 16; i++){
    if (f[i]) ib[base++] = tid * 16 + i;
  }
}

// gather: xcat[b,p,d] = x[b,tok,d] * scale[b,tok] * gamma1[d]
__global__ void k_gather(const float* __restrict__ x, const float* __restrict__ scale,
                         const float* __restrict__ g1, const int* __restrict__ idx,
                         float* __restrict__ xcat){
  size_t i = (size_t)blockIdx.x * 256 + threadIdx.x;
  int d = (int)(i & 511);
  int p = (int)((i >> 9) & (KL_ - 1));
  int b = (int)(i >> 20);
  int tok = idx[(size_t)b * KL_ + p];
  float sc = scale[(size_t)b * N_ + tok];
  xcat[((size_t)b * T_ + p) * D_ + d] = x[((size_t)b * N_ + tok) * D_ + d] * sc * g1[d];
}

// extra row partials: sum over unselected rows of x * scale (gamma applied in stage 2)
__global__ void k_extra1(const float* __restrict__ x, const float* __restrict__ scale,
                         const int* __restrict__ flags, float* __restrict__ part){
  int b = blockIdx.y, blk = blockIdx.x;
  int tid = threadIdx.x;
  const int* fb = flags + (size_t)b * N_ + blk * 256;
  const float* sb = scale + (size_t)b * N_ + blk * 256;
  const float2* xp = (const float2*)(x + ((size_t)b * N_ + blk * 256) * D_) + tid;
  float2 acc = {0.f, 0.f};
  for (int i = 0; i < 256; i++){
    if (!fb[i]){
      float s = sb[i];
      float2 v = xp[(size_t)i * 256];
      acc.x += v.x * s; acc.y += v.y * s;
    }
  }
  float* pr = part + ((size_t)(b * 16 + blk)) * D_;
  pr[tid * 2] = acc.x; pr[tid * 2 + 1] = acc.y;
}

__global__ void k_extra2(const float* __restrict__ part, const float* __restrict__ g1,
                         float* __restrict__ xcat){
  int b = blockIdx.y; int d = blockIdx.x * 256 + threadIdx.x;
  float s = 0.f;
  for (int i = 0; i < 16; i++) s += part[((size_t)(b * 16 + i)) * D_ + d];
  xcat[((size_t)b * T_ + KL_) * D_ + d] = s * g1[d];
}

// rmsnorm2 + fused gate logits/softmax. Writes xn2 (f32), xn2b (bf16), gate.
__global__ void k_rms2gate(const float* __restrict__ xc, const float* __restrict__ g,
                           const float* __restrict__ gw,
                           float* __restrict__ xn2, __hip_bfloat16* __restrict__ xn2b,
                           float* __restrict__ gate){
  __shared__ float sm[4];
  __shared__ float sg[16];
  int row = blockIdx.x; int tid = threadIdx.x;
  const float* xr = xc + (size_t)row * D_;
  float v0 = xr[tid], v1 = xr[tid + 256];
  float ss = block_sum256(v0 * v0 + v1 * v1, sm);
  float n = fmaxf(sqrtf(ss), 1e-12f);
  float inv = 22.627416997969522f / n;
  float xn0 = v0 * inv * g[tid], xn1 = v1 * inv * g[tid + 256];
  float* o = xn2 + (size_t)row * D_;
  o[tid] = xn0; o[tid + 256] = xn1;
  __hip_bfloat16* ob = xn2b + (size_t)row * D_;
  ob[tid] = __float2bfloat16(xn0); ob[tid + 256] = __float2bfloat16(xn1);
  const float4* gw4 = (const float4*)gw;
  float4 wa = gw4[tid], wb = gw4[tid + 256];
  float l0 = xn0 * wa.x + xn1 * wb.x, l1 = xn0 * wa.y + xn1 * wb.y;
  float l2 = xn0 * wa.z + xn1 * wb.z, l3 = xn0 * wa.w + xn1 * wb.w;
  l0 = wave_sum(l0); l1 = wave_sum(l1); l2 = wave_sum(l2); l3 = wave_sum(l3);
  int lane = tid & 63, wid = tid >> 6;
  if (lane == 0){ sg[wid*4+0]=l0; sg[wid*4+1]=l1; sg[wid*4+2]=l2; sg[wid*4+3]=l3; }
  __syncthreads();
  if (tid == 0){
    float a0 = sg[0]+sg[4]+sg[8]+sg[12];
    float a1 = sg[1]+sg[5]+sg[9]+sg[13];
    float a2 = sg[2]+sg[6]+sg[10]+sg[14];
    float a3 = sg[3]+sg[7]+sg[11]+sg[15];
    float m = fmaxf(fmaxf(a0, a1), fmaxf(a2, a3));
    float e0 = expf(a0-m), e1 = expf(a1-m), e2 = expf(a2-m), e3 = expf(a3-m);
    float is = 1.f / (e0+e1+e2+e3);
    float* gr = gate + (size_t)row * 4;
    gr[0]=e0*is; gr[1]=e1*is; gr[2]=e2*is; gr[3]=e3*is;
  }
}

// reduce gate(TOK,4) -> gs[4]. 32 blocks, 128 spread atomics total.
__global__ void k_gsum(const float* __restrict__ gate, float* __restrict__ gs){
  __shared__ float sm[16];
  int tid = threadIdx.x;
  float4 a = {0.f, 0.f, 0.f, 0.f};
  for (int r = blockIdx.x * 256 + tid; r < TOK_; r += gridDim.x * 256){
    float4 v = *(const float4*)(gate + (size_t)r * 4);
    a.x += v.x; a.y += v.y; a.z += v.z; a.w += v.w;
  }
  a.x = wave_sum(a.x); a.y = wave_sum(a.y); a.z = wave_sum(a.z); a.w = wave_sum(a.w);
  int lane = tid & 63, wid = tid >> 6;
  if (lane == 0){ sm[wid*4]=a.x; sm[wid*4+1]=a.y; sm[wid*4+2]=a.z; sm[wid*4+3]=a.w; }
  __syncthreads();
  if (tid < 4){
    float s = sm[tid] + sm[4+tid] + sm[8+tid] + sm[12+tid];
    atomicAdd(&gs[tid], s);
  }
}

// LDS-tiled transpose+convert: in (R x C) f32 -> out (C x R) bf16, batched over z.
__global__ void k_trb(const float* __restrict__ in, __hip_bfloat16* __restrict__ out,
                      int R, int C){
  __shared__ float t[32][33];
  int mat = blockIdx.z;
  in  += (size_t)mat * R * C;
  out += (size_t)mat * R * C;
  int c0 = blockIdx.x * 32, r0 = blockIdx.y * 32;
  int j = threadIdx.x & 31, i4 = threadIdx.x >> 5;
  #pragma unroll
  for (int k = 0; k < 4; k++){
    int i = i4 * 4 + k;
    t[i][j] = in[(size_t)(r0 + i) * C + c0 + j];
  }
  __syncthreads();
  #pragma unroll
  for (int k = 0; k < 4; k++){
    int i = i4 * 4 + k;
    out[(size_t)(c0 + i) * R + r0 + j] = __float2bfloat16(t[j][i]);
  }
}

// ew2 (E,H,D) -> w2b grouped: w2b[(e>>1)*D*2048 + d*2048 + (e&1)*H + h]
__global__ void k_trb2(const float* __restrict__ in, __hip_bfloat16* __restrict__ out){
  __shared__ float t[32][33];
  int e = blockIdx.z;
  const float* ip = in + (size_t)e * H_ * D_;
  __hip_bfloat16* op = out + (size_t)(e >> 1) * D_ * 2048 + (e & 1) * H_;
  int c0 = blockIdx.x * 32, r0 = blockIdx.y * 32;   // c over D, r over H
  int j = threadIdx.x & 31, i4 = threadIdx.x >> 5;
  #pragma unroll
  for (int k = 0; k < 4; k++){
    int i = i4 * 4 + k;
    t[i][j] = ip[(size_t)(r0 + i) * D_ + c0 + j];
  }
  __syncthreads();
  #pragma unroll
  for (int k = 0; k < 4; k++){
    int i = i4 * 4 + k;
    op[(size_t)(c0 + i) * 2048 + r0 + j] = __float2bfloat16(t[j][i]);
  }
}

// pack conv weights (oc,ic,KW) f32 -> wcb bf16 [type][oc][k*32+ic], K zero-padded
__global__ void k_wpack(const float* __restrict__ w39, const float* __restrict__ w19,
                        const float* __restrict__ w9, __hip_bfloat16* __restrict__ wcb){
  int i = blockIdx.x * 256 + threadIdx.x;
  if (i >= 73728) return;
  const float* w; int KP, KW, base;
  if (i < 40960){ w = w39; KP = 40; KW = 39; base = 0; }
  else if (i < 61440){ w = w19; KP = 20; KW = 19; base = 40960; }
  else { w = w9; KP = 12; KW = 9; base = 61440; }
  int li = i - base;
  int oc = li / (32 * KP);
  int rem = li % (32 * KP);
  int k = rem >> 5, ic = rem & 31;
  float v = (k < KW) ? w[((size_t)oc * 32 + ic) * KW + k] : 0.f;
  wcb[i] = __float2bfloat16(v);
}

// bf16 MFMA GEMM, B pre-transposed (Bt: N x K row-major). C = A(MxK) @ B(KxN).
// 128x128 tile, BK=32, 4 waves. EPI 0: Cf = acc;
// EPI 1: Cb = bf16(gelu(acc) * gatep[row*4 + (col>>10)]); EPI 2: Cf += acc.
template<int EPI>
__launch_bounds__(256)
__global__ void gemm_bt(const __hip_bfloat16* __restrict__ A,
                        const __hip_bfloat16* __restrict__ Bt,
                        float* __restrict__ Cf, __hip_bfloat16* __restrict__ Cb,
                        int M, int N, int K, const float* __restrict__ gatep){
  __shared__ __align__(16) char smem[2][16384];   // [buf][A 8K | B 8K]
  int tid = threadIdx.x;
  int m0 = blockIdx.y * 128, n0 = blockIdx.x * 128;
  int ln = tid & 63, wid = tid >> 6;
  int wm = wid >> 1, wn = wid & 1;

  f32x4 acc[4][4] = {};

  auto stage = [&](int buf, int k0){
    #pragma unroll
    for (int c = 0; c < 2; c++){
      int ii = tid + c * 256;
      int r = ii >> 2, s = ii & 3;
      int gm = m0 + r; gm = gm < M ? gm : M - 1;
      const __hip_bfloat16* gp = A + (size_t)gm * K + (k0 + ((s ^ (r & 3)) << 3));
      __builtin_amdgcn_global_load_lds(
          (const __attribute__((address_space(1))) void*)gp,
          (__attribute__((address_space(3))) void*)&smem[buf][ii * 16], 16, 0, 0);
    }
    #pragma unroll
    for (int c = 0; c < 2; c++){
      int ii = tid + c * 256;
      int r = ii >> 2, s = ii & 3;
      const __hip_bfloat16* gp = Bt + (size_t)(n0 + r) * K + (k0 + ((s ^ (r & 3)) << 3));
      __builtin_amdgcn_global_load_lds(
          (const __attribute__((address_space(1))) void*)gp,
          (__attribute__((address_space(3))) void*)&smem[buf][8192 + ii * 16], 16, 0, 0);
    }
  };

  int nk = K >> 5;
  stage(0, 0);
  __syncthreads();
  int slotb = (((ln >> 4) ^ (ln & 3)) << 4);   // swizzled 16B slot for my kgrp
  for (int t = 0; t < nk; t++){
    int buf = t & 1;
    if (t + 1 < nk) stage(buf ^ 1, (t + 1) << 5);
    bf16x8 af[4], bfr[4];
    #pragma unroll
    for (int m = 0; m < 4; m++){
      int R = wm * 64 + m * 16 + (ln & 15);
      af[m] = *(const bf16x8*)&smem[buf][R * 64 + slotb];
    }
    #pragma unroll
    for (int n = 0; n < 4; n++){
      int R = wn * 64 + n * 16 + (ln & 15);
      bfr[n] = *(const bf16x8*)&smem[buf][8192 + R * 64 + slotb];
    }
    #pragma unroll
    for (int m = 0; m < 4; m++)
      #pragma unroll
      for (int n = 0; n < 4; n++)
        acc[m][n] = __builtin_amdgcn_mfma_f32_16x16x32_bf16(af[m], bfr[n], acc[m][n], 0, 0, 0);
    __syncthreads();
  }

  #pragma unroll
  for (int m = 0; m < 4; m++){
    int rb = m0 + wm * 64 + m * 16 + ((ln >> 4) << 2);
    #pragma unroll
    for (int n = 0; n < 4; n++){
      int col = n0 + wn * 64 + n * 16 + (ln & 15);
      #pragma unroll
      for (int r = 0; r < 4; r++){
        int row = rb + r;
        if (row < M){
          size_t ci = (size_t)row * N + col;
          float v = acc[m][n][r];
          if (EPI == 0) Cf[ci] = v;
          else if (EPI == 1)
            Cb[ci] = __float2bfloat16(gelu_f(v) * gatep[(size_t)row * 4 + (col >> 10)]);
          else Cf[ci] += v;
        }
      }
    }
  }
}

// fused 1x1 convs: y=0 -> bott_w -> xbp (bf16, padded layout); y=1 -> mp_w -> cat.
__global__ void k_1x1F(const float* __restrict__ xn2, const float* __restrict__ bw,
                       const float* __restrict__ mw,
                       __hip_bfloat16* __restrict__ xbp, float* __restrict__ cat){
  __shared__ float Xs[32 * 33];
  __shared__ float Ws[32 * 36];
  int type = blockIdx.y;
  const float* w = type == 0 ? bw : mw;
  int tid = threadIdx.x;
  int G0 = blockIdx.x * 32;
  int tok = tid & 31, grp = tid >> 5;
  float acc[4] = {};
  for (int d0 = 0; d0 < D_; d0 += 32){
    {
      int tt = tid >> 3, dc = (tid & 7) * 4;
      int g = G0 + tt;
      float4 v = {0.f, 0.f, 0.f, 0.f};
      if (g < TOK_){
        const float* p = xn2 + (size_t)g * D_ + d0 + dc;
        v = *(const float4*)p;
        if (type == 1){
          int t = g % T_;
          if (t > 0){ float4 u = *(const float4*)(p - D_);
            v.x = fmaxf(v.x, u.x); v.y = fmaxf(v.y, u.y);
            v.z = fmaxf(v.z, u.z); v.w = fmaxf(v.w, u.w); }
          if (t < T_ - 1){ float4 u = *(const float4*)(p + D_);
            v.x = fmaxf(v.x, u.x); v.y = fmaxf(v.y, u.y);
            v.z = fmaxf(v.z, u.z); v.w = fmaxf(v.w, u.w); }
        }
      }
      float* xd = &Xs[tt * 33 + dc];
      xd[0] = v.x; xd[1] = v.y; xd[2] = v.z; xd[3] = v.w;
    }
    for (int j = tid; j < 1024; j += 256){
      int f = j >> 5, d = j & 31;
      Ws[d * 36 + f] = w[(size_t)f * D_ + d0 + d];
    }
    __syncthreads();
    const float* xr = &Xs[tok * 33];
    #pragma unroll 8
    for (int d = 0; d < 32; d++){
      float xv = xr[d];
      const float4* w4 = (const float4*)&Ws[d * 36 + grp * 4];
      float4 a = w4[0];
      acc[0] += xv * a.x; acc[1] += xv * a.y; acc[2] += xv * a.z; acc[3] += xv * a.w;
    }
    __syncthreads();
  }
  int g = G0 + tok;
  if (g < TOK_){
    if (type == 0){
      int bb = g / T_, t = g % T_;
      __hip_bfloat16* op = xbp + ((size_t)(bb * SP_ + 32 + t)) * 32 + grp * 4;
      #pragma unroll
      for (int j = 0; j < 4; j++) op[j] = __float2bfloat16(acc[j]);
    } else {
      float* op = cat + (size_t)g * 128 + 96 + grp * 4;
      #pragma unroll
      for (int j = 0; j < 4; j++) op[j] = acc[j];
    }
  }
}

// MFMA implicit-GEMM conv. Block: 128 tokens x 32 oc, 4 waves (each 32 tok x 32 oc).
template<int KP, int PAD, int OFF, int TYPE>
DEV void convm_body(const __hip_bfloat16* __restrict__ xbp,
                    const __hip_bfloat16* __restrict__ wcb,
                    float* __restrict__ cat, char* smem){
  constexpr int R = KP * 32;
  int t0 = blockIdx.x * 128, b = blockIdx.y;
  int tid = threadIdx.x;
  for (int j = tid; j < 768; j += 256){
    int r = j >> 2, c = j & 3;
    int rg = b * SP_ + 32 + t0 - PAD + r;
    const __hip_bfloat16* gp = xbp + (size_t)rg * 32 + ((c ^ (r & 3)) << 3);
    __builtin_amdgcn_global_load_lds(
        (const __attribute__((address_space(1))) void*)gp,
        (__attribute__((address_space(3))) void*)(smem + j * 16), 16, 0, 0);
  }
  __syncthreads();
  int ln = tid & 63, wid = tid >> 6;
  int lr = ln & 15, lg = ln >> 4;
  int tb = wid * 32;
  const __hip_bfloat16* wt = wcb + OFF;
  const __hip_bfloat16* bp0 = wt + (size_t)lr * R + lg * 8;
  const __hip_bfloat16* bp1 = wt + (size_t)(16 + lr) * R + lg * 8;
  f32x4 acc[2][2] = {};
  bf16x8 bc0 = *(const bf16x8*)bp0;
  bf16x8 bc1 = *(const bf16x8*)bp1;
  #pragma unroll 4
  for (int s = 0; s < KP; s++){
    bf16x8 bn0 = bc0, bn1 = bc1;
    if (s + 1 < KP){
      bn0 = *(const bf16x8*)(bp0 + (s + 1) * 32);
      bn1 = *(const bf16x8*)(bp1 + (s + 1) * 32);
    }
    int ra0 = tb + lr + s;
    int ra1 = tb + 16 + lr + s;
    bf16x8 a0 = *(const bf16x8*)(smem + ra0 * 64 + ((lg ^ (ra0 & 3)) << 4));
    bf16x8 a1 = *(const bf16x8*)(smem + ra1 * 64 + ((lg ^ (ra1 & 3)) << 4));
    acc[0][0] = __builtin_amdgcn_mfma_f32_16x16x32_bf16(a0, bc0, acc[0][0], 0, 0, 0);
    acc[0][1] = __builtin_amdgcn_mfma_f32_16x16x32_bf16(a0, bc1, acc[0][1], 0, 0, 0);
    acc[1][0] = __builtin_amdgcn_mfma_f32_16x16x32_bf16(a1, bc0, acc[1][0], 0, 0, 0);
    acc[1][1] = __builtin_amdgcn_mfma_f32_16x16x32_bf16(a1, bc1, acc[1][1], 0, 0, 0);
    bc0 = bn0; bc1 = bn1;
  }
  #pragma unroll
  for (int m = 0; m < 2; m++){
    int rb = tb + m * 16 + ((ln >> 4) << 2);
    #pragma unroll
    for (int n = 0; n < 2; n++){
      int oc = n * 16 + lr;
      #pragma unroll
      for (int j2 = 0; j2 < 4; j2++){
        int tp = t0 + rb + j2;
        if (tp < T_)
          cat[((size_t)b * T_ + tp) * 128 + TYPE * 32 + oc] = acc[m][n][j2];
      }
    }
  }
}

__global__ __launch_bounds__(256)
void k_convM(const __hip_bfloat16* __restrict__ xbp,
             const __hip_bfloat16* __restrict__ wcb, float* __restrict__ cat){
  __shared__ __align__(16) char smem[192 * 64];
  if (blockIdx.z == 0)      convm_body<40, 19, 0,     0>(xbp, wcb, cat, smem);
  else if (blockIdx.z == 1) convm_body<20, 9,  40960, 1>(xbp, wcb, cat, smem);
  else                      convm_body<12, 4,  61440, 2>(xbp, wcb, cat, smem);
}

// BN stats: coalesced grid-stride, per-channel atomics into stats[0..255]
__global__ void k_bnstat(const float* __restrict__ cat, float* __restrict__ stats){
  __shared__ float sm[512];
  int tid = threadIdx.x;
  float s = 0.f, q = 0.f;
  for (int rp = blockIdx.x; rp < TOK_ / 2; rp += gridDim.x){
    float v = cat[(size_t)rp * 256 + tid];
    s += v; q += v * v;
  }
  sm[tid] = s; sm[256 + tid] = q;
  __syncthreads();
  if (tid < 128){
    atomicAdd(&stats[tid], sm[tid] + sm[tid + 128]);
    atomicAdd(&stats[128 + tid], sm[256 + tid] + sm[256 + tid + 128]);
  }
}

// BN normalize + gelu, output bf16 for the MFMA projection GEMM
__global__ void k_bnact(const float* __restrict__ cat, __hip_bfloat16* __restrict__ catb,
                        const float* __restrict__ stats,
                        const float* __restrict__ g, const float* __restrict__ b){
  int i = blockIdx.x * 256 + threadIdx.x;
  int c = i & 127;
  float mu = stats[c] * (1.f / TOK_);
  float var = stats[128 + c] * (1.f / TOK_) - mu * mu;
  float v = cat[i];
  v = (v - mu) * rsqrtf(var + 1e-5f) * g[c] + b[c];
  catb[i] = __float2bfloat16(gelu_f(v));
}

__global__ void k_final(const float* __restrict__ xcat, const float* __restrict__ moe,
                        const float* __restrict__ iout, const float* __restrict__ pb,
                        float* __restrict__ out){
  size_t i = (size_t)blockIdx.x * 256 + threadIdx.x;
  int d = (int)(i & 511);
  out[i] = gelu_f(xcat[i] + moe[i] + iout[i] + pb[d]);
}

__global__ void k_loss(const float* __restrict__ gsum, float* __restrict__ o){
  if (threadIdx.x == 0){
    float l = 0;
    for (int e = 0; e < E_; e++){ float m = gsum[e] / (float)TOK_; l += m * m; }
    o[0] = (float)E_ * l;
  }
}

extern "C" void kernel_launch(void* const* d_in, const int* in_sizes, int n_in,
                              void* d_out, int out_size, void* d_ws, size_t ws_size,
                              hipStream_t stream){
  const float* x      = (const float*)d_in[0];
  const float* gamma1 = (const float*)d_in[2];
  const float* gamma2 = (const float*)d_in[3];
  const float* attn_w = (const float*)d_in[4];
  const float* attn_b = (const float*)d_in[5];
  const float* gate_w = (const float*)d_in[6];
  const float* ew1    = (const float*)d_in[7];
  const float* ew2    = (const float*)d_in[8];
  const float* bott_w = (const float*)d_in[9];
  const float* w39    = (const float*)d_in[10];
  const float* w19    = (const float*)d_in[11];
  const float* w9     = (const float*)d_in[12];
  const float* mp_w   = (const float*)d_in[13];
  const float* bn_g   = (const float*)d_in[14];
  const float* bn_b   = (const float*)d_in[15];
  const float* proj_w = (const float*)d_in[16];
  const float* proj_b = (const float*)d_in[17];
  float* out = (float*)d_out;

  float* ws = (float*)d_ws;
  size_t off = 0;
  auto alloc = [&](size_t n){ size_t o = off; off += (n + 63) & ~(size_t)63; return o; };
  size_t f_hb   = alloc(8392704);   // hbuf bf16 (TOK x 2048)
  size_t f_sc   = alloc(B_ * N_);
  size_t f_sca  = alloc(B_ * N_);
  size_t f_fl   = alloc(B_ * N_);
  size_t f_idx  = alloc(B_ * KL_);
  size_t f_xcat = alloc((size_t)TOK_ * D_);
  size_t f_xn2  = alloc((size_t)TOK_ * D_);
  size_t f_gate = alloc(TOK_ * E_);
  size_t f_gs   = alloc(64);
  size_t f_st   = alloc(256);
  size_t f_moe  = alloc((size_t)TOK_ * D_);
  size_t f_xbp  = alloc((size_t)B_ * SP_ * 32 / 2);   // bf16 padded conv input
  size_t f_cat  = alloc((size_t)TOK_ * 128);
  size_t f_iout = alloc((size_t)TOK_ * D_);        // hosts w1b,w2b,xn2b (bf16) early
  size_t f_part = alloc((size_t)64 * D_);
  size_t f_wcb  = alloc(73728 / 2 + 64);           // packed conv weights bf16
  size_t f_pjb  = alloc(512 * 128 / 2 + 64);       // projb bf16 (512x128)
  size_t f_catb = alloc((size_t)TOK_ * 128 / 2 + 64); // catb bf16
  (void)ws_size; (void)in_sizes; (void)n_in; (void)out_size;

  float* sc   = ws + f_sc;
  float* sca  = ws + f_sca;
  int*   fl   = (int*)(ws + f_fl);
  int*   idx  = (int*)(ws + f_idx);
  float* xcat = ws + f_xcat;
  float* xn2  = ws + f_xn2;
  float* gate = ws + f_gate;
  float* gs   = ws + f_gs;
  float* stats= ws + f_st;
  float* moe  = ws + f_moe;
  float* cat  = ws + f_cat;
  float* iout = ws + f_iout;
  float* part = ws + f_part;
  __hip_bfloat16* xbp   = (__hip_bfloat16*)(ws + f_xbp);
  __hip_bfloat16* wcb   = (__hip_bfloat16*)(ws + f_wcb);
  __hip_bfloat16* projb = (__hip_bfloat16*)(ws + f_pjb);
  __hip_bfloat16* catb  = (__hip_bfloat16*)(ws + f_catb);
  __hip_bfloat16* hbuf = (__hip_bfloat16*)(ws + f_hb);     // TOK x 2048 bf16 (per group)
  __hip_bfloat16* w1b  = (__hip_bfloat16*)iout;            // [e][h][d]  4.2MB
  __hip_bfloat16* w2b  = w1b + (size_t)E_ * D_ * H_;       // grouped [g][d][2048]  4.2MB
  __hip_bfloat16* xn2b = w2b + (size_t)E_ * D_ * H_;       // TOK x D bf16  8.4MB

  hipMemsetAsync(gs, 0, (64 + 256) * sizeof(float), stream);   // gs + stats
  hipMemsetAsync(xbp, 0, (size_t)B_ * SP_ * 32 * sizeof(__hip_bfloat16), stream);

  // weight preps
  k_trb<<<dim3(H_/32, D_/32, E_), 256, 0, stream>>>(ew1, w1b, D_, H_);   // -> [e][H][D]
  k_trb2<<<dim3(D_/32, H_/32, E_), 256, 0, stream>>>(ew2, w2b);          // -> [g][D][2048]
  k_trb<<<dim3(D_/32, 128/32, 1), 256, 0, stream>>>(proj_w, projb, 128, D_); // -> [512][128]
  k_wpack<<<288, 256, 0, stream>>>(w39, w19, w9, wcb);

  k_rms_score<<<B_ * N_, 256, 0, stream>>>(x, gamma1, attn_w, attn_b, sc, sca);
  k_select<<<dim3(N_ / 64, B_), 256, 0, stream>>>(sc, fl);
  k_compact<<<B_, 256, 0, stream>>>(fl, idx);
  k_gather<<<(B_ * KL_ * D_) / 256, 256, 0, stream>>>(x, sca, gamma1, idx, xcat);
  k_extra1<<<dim3(16, B_), 256, 0, stream>>>(x, sca, fl, part);
  k_extra2<<<dim3(2, B_), 256, 0, stream>>>(part, gamma1, xcat);
  k_rms2gate<<<TOK_, 256, 0, stream>>>(xcat, gamma2, gate_w, xn2, xn2b, gate);
  k_gsum<<<32, 256, 0, stream>>>(gate, gs);

  int mt = (TOK_ + 127) / 128;   // 65
  // group 0: experts {0,1}; group 1: experts {2,3}
  gemm_bt<1><<<dim3(2048/128, mt), 256, 0, stream>>>(
      xn2b, w1b, nullptr, hbuf, TOK_, 2048, D_, gate);
  gemm_bt<0><<<dim3(D_/128, mt), 256, 0, stream>>>(
      hbuf, w2b, moe, nullptr, TOK_, D_, 2048, nullptr);
  gemm_bt<1><<<dim3(2048/128, mt), 256, 0, stream>>>(
      xn2b, w1b + (size_t)2 * H_ * D_, nullptr, hbuf, TOK_, 2048, D_, gate + 2);
  gemm_bt<2><<<dim3(D_/128, mt), 256, 0, stream>>>(
      hbuf, w2b + (size_t)D_ * 2048, moe, nullptr, TOK_, D_, 2048, nullptr);

  int t32 = (TOK_ + 31) / 32;  // 257
  k_1x1F<<<dim3(t32, 2), 256, 0, stream>>>(xn2, bott_w, mp_w, xbp, cat);
  k_convM<<<dim3(17, 4, 3), 256, 0, stream>>>(xbp, wcb, cat);
  k_bnstat<<<64, 256, 0, stream>>>(cat, stats);
  k_bnact<<<(TOK_ * 128) / 256, 256, 0, stream>>>(cat, catb, stats, bn_g, bn_b);
  gemm_bt<0><<<dim3(D_/128, mt), 256, 0, stream>>>(
      catb, projb, iout, nullptr, TOK_, D_, 128, nullptr);
  k_final<<<((size_t)TOK_ * D_) / 256, 256, 0, stream>>>(xcat, moe, iout, proj_b, out);
  k_loss<<<1, 64, 0, stream>>>(gs, out + (size_t)TOK_ * D_);
}